// Round 1
// baseline (3497.826 us; speedup 1.0000x reference)
//
#include <hip/hip_runtime.h>
#include <cmath>

#define DD 64
#define TILE 64
#define BLK 256

__device__ __forceinline__ float elu_f(float x) {
  return x > 0.f ? x : expm1f(x);
}

// 64x64 tile matmul: acc[4][4] += xs_tile @ wl ; thread (tr,tc) owns rows r0..r0+3, cols c0..c0+3
__device__ __forceinline__ void matmul_tile(const float xs[TILE][DD + 4],
                                            const float wl[DD][DD],
                                            int r0, int c0, float acc[4][4]) {
#pragma unroll
  for (int k0 = 0; k0 < DD; k0 += 4) {
    float4 xv[4], wv[4];
#pragma unroll
    for (int i = 0; i < 4; ++i) xv[i] = *(const float4*)&xs[r0 + i][k0];
#pragma unroll
    for (int j = 0; j < 4; ++j) wv[j] = *(const float4*)&wl[k0 + j][c0];
#pragma unroll
    for (int i = 0; i < 4; ++i) {
      const float* xp = (const float*)&xv[i];
#pragma unroll
      for (int kk = 0; kk < 4; ++kk) {
        const float xk = xp[kk];
        const float* wp = (const float*)&wv[kk];
#pragma unroll
        for (int j = 0; j < 4; ++j) acc[i][j] += xk * wp[j];
      }
    }
  }
}

// ---------------- counts per molecule ----------------
__global__ void cnt_kernel(const int* __restrict__ a2m, int na,
                           const int* __restrict__ b2m, int nb,
                           float* __restrict__ cnta, float* __restrict__ cntb) {
  int i = blockIdx.x * blockDim.x + threadIdx.x;
  if (i < na) atomicAdd(&cnta[a2m[i]], 1.f);
  else if (i < na + nb) atomicAdd(&cntb[b2m[i - na]], 1.f);
}

// ---------------- dual linear: out0 = x@W0+b0, out1 = x@W1+b1 ----------------
__global__ __launch_bounds__(BLK) void lin2_kernel(
    const float* __restrict__ x, int nrows,
    const float* __restrict__ W0, const float* __restrict__ b0, float* __restrict__ out0,
    const float* __restrict__ W1, const float* __restrict__ b1, float* __restrict__ out1) {
  __shared__ __align__(16) float xs[TILE][DD + 4];
  __shared__ __align__(16) float w0[DD][DD];
  __shared__ __align__(16) float w1[DD][DD];
  const int tid = threadIdx.x;
  const int base = blockIdx.x * TILE;
  int rows = nrows - base; if (rows > TILE) rows = TILE;
  for (int l = tid; l < DD * DD; l += BLK) {
    int r = l >> 6, c = l & 63;
    xs[r][c] = (r < rows) ? x[(size_t)(base + r) * DD + c] : 0.f;
    w0[r][c] = W0[l];
    w1[r][c] = W1[l];
  }
  __syncthreads();
  const int tr = tid >> 4, tc = tid & 15;
  const int r0 = tr * 4, c0 = tc * 4;
  float a0[4][4] = {{0}}, a1[4][4] = {{0}};
#pragma unroll
  for (int k0 = 0; k0 < DD; k0 += 4) {
    float4 xv[4], wa[4], wb[4];
#pragma unroll
    for (int i = 0; i < 4; ++i) xv[i] = *(const float4*)&xs[r0 + i][k0];
#pragma unroll
    for (int j = 0; j < 4; ++j) {
      wa[j] = *(const float4*)&w0[k0 + j][c0];
      wb[j] = *(const float4*)&w1[k0 + j][c0];
    }
#pragma unroll
    for (int i = 0; i < 4; ++i) {
      const float* xp = (const float*)&xv[i];
#pragma unroll
      for (int kk = 0; kk < 4; ++kk) {
        const float xk = xp[kk];
        const float* wap = (const float*)&wa[kk];
        const float* wbp = (const float*)&wb[kk];
#pragma unroll
        for (int j = 0; j < 4; ++j) {
          a0[i][j] += xk * wap[j];
          a1[i][j] += xk * wbp[j];
        }
      }
    }
  }
  float4 bv0 = *(const float4*)&b0[c0];
  float4 bv1 = *(const float4*)&b1[c0];
  const float* b0p = (const float*)&bv0;
  const float* b1p = (const float*)&bv1;
#pragma unroll
  for (int i = 0; i < 4; ++i) {
    if (r0 + i < rows) {
      size_t rb = (size_t)(base + r0 + i) * DD + c0;
      float4 o0, o1;
      float* o0p = (float*)&o0; float* o1p = (float*)&o1;
#pragma unroll
      for (int j = 0; j < 4; ++j) { o0p[j] = a0[i][j] + b0p[j]; o1p[j] = a1[i][j] + b1p[j]; }
      *(float4*)&out0[rb] = o0;
      *(float4*)&out1[rb] = o1;
    }
  }
}

// ---------------- bond pass 1: e_pre = (Ah[u]+Ah[v]+e@W1+b1+Cu[m])*norm ; BN stats ----------------
__global__ __launch_bounds__(BLK) void bond1_kernel(
    const float* __restrict__ e, int nrows, int ntiles,
    const float* __restrict__ W1, const float* __restrict__ b1,
    const float* __restrict__ Ah, const float* __restrict__ Cu,
    const int* __restrict__ bu, const int* __restrict__ bv, const int* __restrict__ b2m,
    const float* __restrict__ nrm,
    float* __restrict__ e_pre,
    float* __restrict__ ssum, float* __restrict__ ssq) {
  __shared__ __align__(16) float xs[TILE][DD + 4];
  __shared__ __align__(16) float wl[DD][DD];
  __shared__ int sbu[TILE], sbv[TILE], sbm[TILE];
  __shared__ float snb[TILE];
  __shared__ float red[16][DD];
  const int tid = threadIdx.x;
  const int tr = tid >> 4, tc = tid & 15, r0 = tr * 4, c0 = tc * 4;
  for (int l = tid; l < DD * DD; l += BLK) wl[l >> 6][l & 63] = W1[l];
  float4 bv4 = *(const float4*)&b1[c0];
  const float* bp = (const float*)&bv4;
  float lsum[4] = {0, 0, 0, 0}, lsq[4] = {0, 0, 0, 0};
  for (int tile = blockIdx.x; tile < ntiles; tile += gridDim.x) {
    const int base = tile * TILE;
    int rows = nrows - base; if (rows > TILE) rows = TILE;
    __syncthreads();
    for (int l = tid; l < TILE * DD; l += BLK) {
      int r = l >> 6, c = l & 63;
      xs[r][c] = (r < rows) ? e[(size_t)(base + r) * DD + c] : 0.f;
    }
    if (tid < TILE) {
      bool v = tid < rows;
      int rb = base + tid;
      sbu[tid] = v ? bu[rb] : 0;
      sbv[tid] = v ? bv[rb] : 0;
      sbm[tid] = v ? b2m[rb] : 0;
      snb[tid] = v ? nrm[rb] : 0.f;
    }
    __syncthreads();
    float acc[4][4] = {{0}};
    matmul_tile(xs, wl, r0, c0, acc);
#pragma unroll
    for (int i = 0; i < 4; ++i) {
      int r = r0 + i;
      if (r < rows) {
        int rb = base + r;
        float nb = snb[r];
        float4 ga = *(const float4*)&Ah[(size_t)sbu[r] * DD + c0];
        float4 gb = *(const float4*)&Ah[(size_t)sbv[r] * DD + c0];
        float4 gc = *(const float4*)&Cu[(size_t)sbm[r] * DD + c0];
        const float* gap = (const float*)&ga;
        const float* gbp = (const float*)&gb;
        const float* gcp = (const float*)&gc;
        float4 o; float* op = (float*)&o;
#pragma unroll
        for (int j = 0; j < 4; ++j) {
          float v = (acc[i][j] + bp[j] + gap[j] + gbp[j] + gcp[j]) * nb;
          op[j] = v;
          lsum[j] += v;
          lsq[j] += v * v;
        }
        *(float4*)&e_pre[(size_t)rb * DD + c0] = o;
      }
    }
  }
  __syncthreads();
#pragma unroll
  for (int j = 0; j < 4; ++j) red[tr][c0 + j] = lsum[j];
  __syncthreads();
  if (tid < DD) {
    float s = 0.f;
#pragma unroll
    for (int t = 0; t < 16; ++t) s += red[t][tid];
    atomicAdd(&ssum[tid], s);
  }
  __syncthreads();
#pragma unroll
  for (int j = 0; j < 4; ++j) red[tr][c0 + j] = lsq[j];
  __syncthreads();
  if (tid < DD) {
    float s = 0.f;
#pragma unroll
    for (int t = 0; t < 16; ++t) s += red[t][tid];
    atomicAdd(&ssq[tid], s);
  }
}

// ---------------- BN finalize: scale/shift ----------------
__global__ void bnfinal_kernel(const float* __restrict__ ssum, const float* __restrict__ ssq,
                               const float* __restrict__ gamma, const float* __restrict__ beta,
                               float invN, float* __restrict__ scale, float* __restrict__ shift) {
  int j = threadIdx.x;
  float m = ssum[j] * invN;
  float v = ssq[j] * invN - m * m;
  float sc = gamma[j] * rsqrtf(v + 1e-5f);
  scale[j] = sc;
  shift[j] = beta[j] - m * sc;
}

// ---------------- bond pass 2: BN+ELU e (in place), sigmoid gate scatter, He matmul -> mol acc ----------------
__global__ __launch_bounds__(BLK) void bond2_kernel(
    float* __restrict__ e_io, int nrows,
    const float* __restrict__ scale, const float* __restrict__ shift,
    const float* __restrict__ Eh,
    const int* __restrict__ bu, const int* __restrict__ bv, const int* __restrict__ b2m,
    const float* __restrict__ W7, const float* __restrict__ b7,
    float* __restrict__ num, float* __restrict__ den, float* __restrict__ uaccb) {
  __shared__ __align__(16) float xs[TILE][DD + 4];
  __shared__ __align__(16) float wl[DD][DD];
  __shared__ int sbu[TILE], sbv[TILE], sbm[TILE];
  const int tid = threadIdx.x;
  const int base = blockIdx.x * TILE;
  int rows = nrows - base; if (rows > TILE) rows = TILE;
  for (int l = tid; l < DD * DD; l += BLK) wl[l >> 6][l & 63] = W7[l];
  if (tid < TILE) {
    bool v = tid < rows;
    int rb = base + tid;
    sbu[tid] = v ? bu[rb] : 0;
    sbv[tid] = v ? bv[rb] : 0;
    sbm[tid] = v ? b2m[rb] : 0;
  }
  __syncthreads();
  for (int l = tid; l < TILE * DD; l += BLK) {
    int r = l >> 6, c = l & 63;
    float en = 0.f;
    if (r < rows) {
      int rb = base + r;
      float xp = e_io[(size_t)rb * DD + c];
      float xn = xp * scale[c] + shift[c];
      en = elu_f(xn);
      e_io[(size_t)rb * DD + c] = en;
      float sg = 1.f / (1.f + expf(-en));
      int iu = sbu[r], iv = sbv[r];
      float ehv = Eh[(size_t)iv * DD + c];
      float ehu = Eh[(size_t)iu * DD + c];
      atomicAdd(&num[(size_t)iu * DD + c], sg * ehv);
      atomicAdd(&num[(size_t)iv * DD + c], sg * ehu);
      atomicAdd(&den[(size_t)iu * DD + c], sg);
      atomicAdd(&den[(size_t)iv * DD + c], sg);
    }
    xs[r][c] = en;
  }
  __syncthreads();
  const int tr = tid >> 4, tc = tid & 15, r0 = tr * 4, c0 = tc * 4;
  float acc[4][4] = {{0}};
  matmul_tile(xs, wl, r0, c0, acc);
  float4 bv4 = *(const float4*)&b7[c0];
  const float* bp = (const float*)&bv4;
#pragma unroll
  for (int i = 0; i < 4; ++i) {
    int r = r0 + i;
    if (r < rows) {
      float* dst = &uaccb[(size_t)sbm[r] * DD + c0];
#pragma unroll
      for (int j = 0; j < 4; ++j) atomicAdd(&dst[j], acc[i][j] + bp[j]);
    }
  }
}

// ---------------- atom pass 1: h_pre = (h@W3+b3 + num/(den+eps) + Fu[m])*norm ; BN stats ----------------
__global__ __launch_bounds__(BLK) void atom1_kernel(
    const float* __restrict__ h, int nrows, int ntiles,
    const float* __restrict__ W3, const float* __restrict__ b3,
    const float* __restrict__ den, const float* __restrict__ Fu,
    const int* __restrict__ a2m, const float* __restrict__ nrm,
    float* __restrict__ hio,  // num in, h_pre out (same buffer)
    float* __restrict__ ssum, float* __restrict__ ssq) {
  __shared__ __align__(16) float xs[TILE][DD + 4];
  __shared__ __align__(16) float wl[DD][DD];
  __shared__ int sam[TILE];
  __shared__ float sna[TILE];
  __shared__ float red[16][DD];
  const int tid = threadIdx.x;
  const int tr = tid >> 4, tc = tid & 15, r0 = tr * 4, c0 = tc * 4;
  for (int l = tid; l < DD * DD; l += BLK) wl[l >> 6][l & 63] = W3[l];
  float4 bv4 = *(const float4*)&b3[c0];
  const float* bp = (const float*)&bv4;
  float lsum[4] = {0, 0, 0, 0}, lsq[4] = {0, 0, 0, 0};
  for (int tile = blockIdx.x; tile < ntiles; tile += gridDim.x) {
    const int base = tile * TILE;
    int rows = nrows - base; if (rows > TILE) rows = TILE;
    __syncthreads();
    for (int l = tid; l < TILE * DD; l += BLK) {
      int r = l >> 6, c = l & 63;
      xs[r][c] = (r < rows) ? h[(size_t)(base + r) * DD + c] : 0.f;
    }
    if (tid < TILE) {
      bool v = tid < rows;
      int rb = base + tid;
      sam[tid] = v ? a2m[rb] : 0;
      sna[tid] = v ? nrm[rb] : 0.f;
    }
    __syncthreads();
    float acc[4][4] = {{0}};
    matmul_tile(xs, wl, r0, c0, acc);
#pragma unroll
    for (int i = 0; i < 4; ++i) {
      int r = r0 + i;
      if (r < rows) {
        size_t rb = (size_t)(base + r) * DD + c0;
        float na = sna[r];
        float4 n4 = *(const float4*)&hio[rb];
        float4 d4 = *(const float4*)&den[rb];
        float4 f4 = *(const float4*)&Fu[(size_t)sam[r] * DD + c0];
        const float* np = (const float*)&n4;
        const float* dp = (const float*)&d4;
        const float* fp = (const float*)&f4;
        float4 o; float* op = (float*)&o;
#pragma unroll
        for (int j = 0; j < 4; ++j) {
          float v = (acc[i][j] + bp[j] + np[j] / (dp[j] + 1e-6f) + fp[j]) * na;
          op[j] = v;
          lsum[j] += v;
          lsq[j] += v * v;
        }
        *(float4*)&hio[rb] = o;
      }
    }
  }
  __syncthreads();
#pragma unroll
  for (int j = 0; j < 4; ++j) red[tr][c0 + j] = lsum[j];
  __syncthreads();
  if (tid < DD) {
    float s = 0.f;
#pragma unroll
    for (int t = 0; t < 16; ++t) s += red[t][tid];
    atomicAdd(&ssum[tid], s);
  }
  __syncthreads();
#pragma unroll
  for (int j = 0; j < 4; ++j) red[tr][c0 + j] = lsq[j];
  __syncthreads();
  if (tid < DD) {
    float s = 0.f;
#pragma unroll
    for (int t = 0; t < 16; ++t) s += red[t][tid];
    atomicAdd(&ssq[tid], s);
  }
}

// ---------------- atom pass 2: BN+ELU h (in place), Gh matmul -> mol acc ----------------
__global__ __launch_bounds__(BLK) void atom2_kernel(
    float* __restrict__ hio, int nrows,
    const float* __restrict__ scale, const float* __restrict__ shift,
    const int* __restrict__ a2m,
    const float* __restrict__ W6, const float* __restrict__ b6,
    float* __restrict__ uacca) {
  __shared__ __align__(16) float xs[TILE][DD + 4];
  __shared__ __align__(16) float wl[DD][DD];
  __shared__ int sam[TILE];
  const int tid = threadIdx.x;
  const int base = blockIdx.x * TILE;
  int rows = nrows - base; if (rows > TILE) rows = TILE;
  for (int l = tid; l < DD * DD; l += BLK) wl[l >> 6][l & 63] = W6[l];
  if (tid < TILE) {
    sam[tid] = (tid < rows) ? a2m[base + tid] : 0;
  }
  __syncthreads();
  for (int l = tid; l < TILE * DD; l += BLK) {
    int r = l >> 6, c = l & 63;
    float hn = 0.f;
    if (r < rows) {
      size_t rb = (size_t)(base + r) * DD + c;
      float xp = hio[rb];
      float xn = xp * scale[c] + shift[c];
      hn = elu_f(xn);
      hio[rb] = hn;
    }
    xs[r][c] = hn;
  }
  __syncthreads();
  const int tr = tid >> 4, tc = tid & 15, r0 = tr * 4, c0 = tc * 4;
  float acc[4][4] = {{0}};
  matmul_tile(xs, wl, r0, c0, acc);
  float4 bv4 = *(const float4*)&b6[c0];
  const float* bp = (const float*)&bv4;
#pragma unroll
  for (int i = 0; i < 4; ++i) {
    int r = r0 + i;
    if (r < rows) {
      float* dst = &uacca[(size_t)sam[r] * DD + c0];
#pragma unroll
      for (int j = 0; j < 4; ++j) atomicAdd(&dst[j], acc[i][j] + bp[j]);
    }
  }
}

// ---------------- global pass: u_pre = acc_a/cnt_a + acc_b/cnt_b + u@W8+b8 ; BN stats ----------------
__global__ __launch_bounds__(BLK) void global1_kernel(
    const float* __restrict__ u, int nrows,
    const float* __restrict__ W8, const float* __restrict__ b8,
    const float* __restrict__ uacca, const float* __restrict__ uaccb,
    const float* __restrict__ cnta, const float* __restrict__ cntb,
    float* __restrict__ upre,
    float* __restrict__ ssum, float* __restrict__ ssq) {
  __shared__ __align__(16) float xs[TILE][DD + 4];
  __shared__ __align__(16) float wl[DD][DD];
  __shared__ float sca[TILE], scb[TILE];
  __shared__ float red[16][DD];
  const int tid = threadIdx.x;
  const int base = blockIdx.x * TILE;
  int rows = nrows - base; if (rows > TILE) rows = TILE;
  for (int l = tid; l < DD * DD; l += BLK) wl[l >> 6][l & 63] = W8[l];
  for (int l = tid; l < TILE * DD; l += BLK) {
    int r = l >> 6, c = l & 63;
    xs[r][c] = (r < rows) ? u[(size_t)(base + r) * DD + c] : 0.f;
  }
  if (tid < TILE) {
    bool v = tid < rows;
    float ca = v ? cnta[base + tid] : 1.f;
    float cb = v ? cntb[base + tid] : 1.f;
    sca[tid] = ca < 1.f ? 1.f : ca;
    scb[tid] = cb < 1.f ? 1.f : cb;
  }
  __syncthreads();
  const int tr = tid >> 4, tc = tid & 15, r0 = tr * 4, c0 = tc * 4;
  float acc[4][4] = {{0}};
  matmul_tile(xs, wl, r0, c0, acc);
  float4 bv4 = *(const float4*)&b8[c0];
  const float* bp = (const float*)&bv4;
  float lsum[4] = {0, 0, 0, 0}, lsq[4] = {0, 0, 0, 0};
#pragma unroll
  for (int i = 0; i < 4; ++i) {
    int r = r0 + i;
    if (r < rows) {
      size_t rb = (size_t)(base + r) * DD + c0;
      float rca = 1.f / sca[r], rcb = 1.f / scb[r];
      float4 a4 = *(const float4*)&uacca[rb];
      float4 b4 = *(const float4*)&uaccb[rb];
      const float* ap = (const float*)&a4;
      const float* bbp = (const float*)&b4;
      float4 o; float* op = (float*)&o;
#pragma unroll
      for (int j = 0; j < 4; ++j) {
        float v = ap[j] * rca + bbp[j] * rcb + acc[i][j] + bp[j];
        op[j] = v;
        lsum[j] += v;
        lsq[j] += v * v;
      }
      *(float4*)&upre[rb] = o;
    }
  }
  __syncthreads();
#pragma unroll
  for (int j = 0; j < 4; ++j) red[tr][c0 + j] = lsum[j];
  __syncthreads();
  if (tid < DD) {
    float s = 0.f;
#pragma unroll
    for (int t = 0; t < 16; ++t) s += red[t][tid];
    atomicAdd(&ssum[tid], s);
  }
  __syncthreads();
#pragma unroll
  for (int j = 0; j < 4; ++j) red[tr][c0 + j] = lsq[j];
  __syncthreads();
  if (tid < DD) {
    float s = 0.f;
#pragma unroll
    for (int t = 0; t < 16; ++t) s += red[t][tid];
    atomicAdd(&ssq[tid], s);
  }
}

// ---------------- final BN+ELU on u (in place) ----------------
__global__ void bn_elu_kernel(float* __restrict__ x, int n,
                              const float* __restrict__ scale, const float* __restrict__ shift) {
  int i = blockIdx.x * blockDim.x + threadIdx.x;
  if (i < n) {
    int c = i & 63;
    float v = x[i] * scale[c] + shift[c];
    x[i] = elu_f(v);
  }
}

extern "C" void kernel_launch(void* const* d_in, const int* in_sizes, int n_in,
                              void* d_out, int out_size, void* d_ws, size_t ws_size,
                              hipStream_t stream) {
  const float* h         = (const float*)d_in[0];
  const float* e         = (const float*)d_in[1];
  const float* u         = (const float*)d_in[2];
  const float* norm_atom = (const float*)d_in[3];
  const float* norm_bond = (const float*)d_in[4];
  const float* Ws        = (const float*)d_in[5];
  const float* bsarr     = (const float*)d_in[6];
  const float* bn_gamma  = (const float*)d_in[7];
  const float* bn_beta   = (const float*)d_in[8];
  const int* bond_u      = (const int*)d_in[9];
  const int* bond_v      = (const int*)d_in[10];
  const int* a2m         = (const int*)d_in[11];
  const int* b2m         = (const int*)d_in[12];

  const int NA = in_sizes[0] / DD;
  const int NB = in_sizes[1] / DD;
  const int NM = in_sizes[2] / DD;

  float* out_h = (float*)d_out;
  float* out_e = out_h + (size_t)NA * DD;
  float* out_u = out_e + (size_t)NB * DD;

  // workspace layout (~138 MB): Ah(=den after bond1) | Eh | Cu | Fu | uacca | uaccb | cnta | cntb | stats | bnparams
  float* f    = (float*)d_ws;
  float* Ah   = f;                         // NA*64, reused as den after bond pass 1
  float* den  = Ah;
  float* Eh   = Ah + (size_t)NA * DD;
  float* Cu   = Eh + (size_t)NA * DD;
  float* Fu   = Cu + (size_t)NM * DD;
  float* uacca = Fu + (size_t)NM * DD;
  float* uaccb = uacca + (size_t)NM * DD;
  float* cnta  = uaccb + (size_t)NM * DD;
  float* cntb  = cnta + NM;
  float* stats = cntb + NM;                 // 6*64
  float* sum_e = stats, *sq_e = stats + 64;
  float* sum_h = stats + 128, *sq_h = stats + 192;
  float* sum_u = stats + 256, *sq_u = stats + 320;
  float* bnp  = stats + 384;                // 6*64
  float* sc_e = bnp, *sh_e = bnp + 64;
  float* sc_h = bnp + 128, *sh_h = bnp + 192;
  float* sc_u = bnp + 256, *sh_u = bnp + 320;

  const float* W0 = Ws + 0 * 4096; const float* b0 = bsarr + 0 * 64;
  const float* W1 = Ws + 1 * 4096; const float* b1 = bsarr + 1 * 64;
  const float* W2 = Ws + 2 * 4096; const float* b2 = bsarr + 2 * 64;
  const float* W3 = Ws + 3 * 4096; const float* b3 = bsarr + 3 * 64;
  const float* W4 = Ws + 4 * 4096; const float* b4 = bsarr + 4 * 64;
  const float* W5 = Ws + 5 * 4096; const float* b5 = bsarr + 5 * 64;
  const float* W6 = Ws + 6 * 4096; const float* b6 = bsarr + 6 * 64;
  const float* W7 = Ws + 7 * 4096; const float* b7 = bsarr + 7 * 64;
  const float* W8 = Ws + 8 * 4096; const float* b8 = bsarr + 8 * 64;

  const int tiles_a = (NA + TILE - 1) / TILE;
  const int tiles_b = (NB + TILE - 1) / TILE;
  const int tiles_m = (NM + TILE - 1) / TILE;

  // zero accumulators: uacca, uaccb, cnta, cntb, stats
  size_t zcount = (size_t)NM * DD * 2 + (size_t)NM * 2 + 384;
  hipMemsetAsync(uacca, 0, zcount * sizeof(float), stream);

  {
    int n = NA + NB;
    cnt_kernel<<<(n + BLK - 1) / BLK, BLK, 0, stream>>>(a2m, NA, b2m, NB, cnta, cntb);
  }

  lin2_kernel<<<tiles_a, BLK, 0, stream>>>(h, NA, W0, b0, Ah, W4, b4, Eh);
  lin2_kernel<<<tiles_m, BLK, 0, stream>>>(u, NM, W2, b2, Cu, W5, b5, Fu);

  int nblk_b = tiles_b < 2048 ? tiles_b : 2048;
  bond1_kernel<<<nblk_b, BLK, 0, stream>>>(e, NB, tiles_b, W1, b1, Ah, Cu,
                                           bond_u, bond_v, b2m, norm_bond,
                                           out_e, sum_e, sq_e);
  bnfinal_kernel<<<1, 64, 0, stream>>>(sum_e, sq_e, bn_gamma + 0, bn_beta + 0,
                                       1.f / (float)NB, sc_e, sh_e);

  // den reuses Ah's region (Ah dead after bond1); num lives in out_h
  hipMemsetAsync(den, 0, (size_t)NA * DD * sizeof(float), stream);
  hipMemsetAsync(out_h, 0, (size_t)NA * DD * sizeof(float), stream);

  bond2_kernel<<<tiles_b, BLK, 0, stream>>>(out_e, NB, sc_e, sh_e, Eh,
                                            bond_u, bond_v, b2m, W7, b7,
                                            out_h, den, uaccb);

  int nblk_a = tiles_a < 2048 ? tiles_a : 2048;
  atom1_kernel<<<nblk_a, BLK, 0, stream>>>(h, NA, tiles_a, W3, b3, den, Fu,
                                           a2m, norm_atom, out_h, sum_h, sq_h);
  bnfinal_kernel<<<1, 64, 0, stream>>>(sum_h, sq_h, bn_gamma + 64, bn_beta + 64,
                                       1.f / (float)NA, sc_h, sh_h);

  atom2_kernel<<<tiles_a, BLK, 0, stream>>>(out_h, NA, sc_h, sh_h, a2m, W6, b6, uacca);

  global1_kernel<<<tiles_m, BLK, 0, stream>>>(u, NM, W8, b8, uacca, uaccb,
                                              cnta, cntb, out_u, sum_u, sq_u);
  bnfinal_kernel<<<1, 64, 0, stream>>>(sum_u, sq_u, bn_gamma + 128, bn_beta + 128,
                                       1.f / (float)NM, sc_u, sh_u);
  bn_elu_kernel<<<((size_t)NM * DD + BLK - 1) / BLK, BLK, 0, stream>>>(out_u, NM * DD, sc_u, sh_u);
}

// Round 2
// 1062.502 us; speedup vs baseline: 3.2921x; 3.2921x over previous
//
#include <hip/hip_runtime.h>
#include <cmath>

#define DD 64
#define TILE 64
#define BLK 256

__device__ __forceinline__ float elu_f(float x) {
  return x > 0.f ? x : expm1f(x);
}

__device__ __forceinline__ void fma4(float4& a, float s, const float4 b) {
  a.x = fmaf(s, b.x, a.x);
  a.y = fmaf(s, b.y, a.y);
  a.z = fmaf(s, b.z, a.z);
  a.w = fmaf(s, b.w, a.w);
}
__device__ __forceinline__ void add4(float4& a, const float4 b) {
  a.x += b.x; a.y += b.y; a.z += b.z; a.w += b.w;
}
__device__ __forceinline__ void sqacc4(float4& a, const float4 b) {
  a.x = fmaf(b.x, b.x, a.x);
  a.y = fmaf(b.y, b.y, a.y);
  a.z = fmaf(b.z, b.z, a.z);
  a.w = fmaf(b.w, b.w, a.w);
}
__device__ __forceinline__ void scale4(float4& a, float s) {
  a.x *= s; a.y *= s; a.z *= s; a.w *= s;
}

// single-weight 64x64 micro-kernel: acc[i] (i=0..3 rows r0+i) += xs @ wl (cols c0..c0+3)
__device__ __forceinline__ void matmul_tile(const float (*xs)[DD + 4], const float (*wl)[DD],
                                            int r0, int c0, float4 acc[4]) {
#pragma unroll 2
  for (int k0 = 0; k0 < DD; k0 += 4) {
    float4 x0 = *(const float4*)&xs[r0 + 0][k0];
    float4 x1 = *(const float4*)&xs[r0 + 1][k0];
    float4 x2 = *(const float4*)&xs[r0 + 2][k0];
    float4 x3 = *(const float4*)&xs[r0 + 3][k0];
    float4 w0 = *(const float4*)&wl[k0 + 0][c0];
    float4 w1 = *(const float4*)&wl[k0 + 1][c0];
    float4 w2 = *(const float4*)&wl[k0 + 2][c0];
    float4 w3 = *(const float4*)&wl[k0 + 3][c0];
    fma4(acc[0], x0.x, w0); fma4(acc[0], x0.y, w1); fma4(acc[0], x0.z, w2); fma4(acc[0], x0.w, w3);
    fma4(acc[1], x1.x, w0); fma4(acc[1], x1.y, w1); fma4(acc[1], x1.z, w2); fma4(acc[1], x1.w, w3);
    fma4(acc[2], x2.x, w0); fma4(acc[2], x2.y, w1); fma4(acc[2], x2.z, w2); fma4(acc[2], x2.w, w3);
    fma4(acc[3], x3.x, w0); fma4(acc[3], x3.y, w1); fma4(acc[3], x3.z, w2); fma4(acc[3], x3.w, w3);
  }
}

// ---------------- counts per molecule ----------------
__global__ void cnt_kernel(const int* __restrict__ a2m, int na,
                           const int* __restrict__ b2m, int nb,
                           float* __restrict__ cnta, float* __restrict__ cntb) {
  int i = blockIdx.x * blockDim.x + threadIdx.x;
  if (i < na) atomicAdd(&cnta[a2m[i]], 1.f);
  else if (i < na + nb) atomicAdd(&cntb[b2m[i - na]], 1.f);
}

// ---------------- dual linear: out0 = x@W0+b0, out1 = x@W1+b1 ----------------
__global__ __launch_bounds__(BLK) void lin2_kernel(
    const float* __restrict__ x, int nrows,
    const float* __restrict__ W0, const float* __restrict__ b0, float* __restrict__ out0,
    const float* __restrict__ W1, const float* __restrict__ b1, float* __restrict__ out1) {
  __shared__ __align__(16) float xs[TILE][DD + 4];
  __shared__ __align__(16) float w0[DD][DD];
  __shared__ __align__(16) float w1[DD][DD];
  const int tid = threadIdx.x;
  const int base = blockIdx.x * TILE;
  int rows = nrows - base; if (rows > TILE) rows = TILE;
  for (int l = tid; l < DD * DD; l += BLK) {
    int r = l >> 6, c = l & 63;
    xs[r][c] = (r < rows) ? x[(size_t)(base + r) * DD + c] : 0.f;
    w0[r][c] = W0[l];
    w1[r][c] = W1[l];
  }
  __syncthreads();
  const int tr = tid >> 4, tc = tid & 15;
  const int r0 = tr * 4, c0 = tc * 4;
  float4 accA[4], accB[4];
#pragma unroll
  for (int i = 0; i < 4; ++i) {
    accA[i] = make_float4(0.f, 0.f, 0.f, 0.f);
    accB[i] = make_float4(0.f, 0.f, 0.f, 0.f);
  }
#pragma unroll 1
  for (int k0 = 0; k0 < DD; k0 += 4) {
    float4 x0 = *(const float4*)&xs[r0 + 0][k0];
    float4 x1 = *(const float4*)&xs[r0 + 1][k0];
    float4 x2 = *(const float4*)&xs[r0 + 2][k0];
    float4 x3 = *(const float4*)&xs[r0 + 3][k0];
    float4 wa0 = *(const float4*)&w0[k0 + 0][c0];
    float4 wa1 = *(const float4*)&w0[k0 + 1][c0];
    float4 wa2 = *(const float4*)&w0[k0 + 2][c0];
    float4 wa3 = *(const float4*)&w0[k0 + 3][c0];
    float4 wb0 = *(const float4*)&w1[k0 + 0][c0];
    float4 wb1 = *(const float4*)&w1[k0 + 1][c0];
    float4 wb2 = *(const float4*)&w1[k0 + 2][c0];
    float4 wb3 = *(const float4*)&w1[k0 + 3][c0];
    fma4(accA[0], x0.x, wa0); fma4(accA[0], x0.y, wa1); fma4(accA[0], x0.z, wa2); fma4(accA[0], x0.w, wa3);
    fma4(accA[1], x1.x, wa0); fma4(accA[1], x1.y, wa1); fma4(accA[1], x1.z, wa2); fma4(accA[1], x1.w, wa3);
    fma4(accA[2], x2.x, wa0); fma4(accA[2], x2.y, wa1); fma4(accA[2], x2.z, wa2); fma4(accA[2], x2.w, wa3);
    fma4(accA[3], x3.x, wa0); fma4(accA[3], x3.y, wa1); fma4(accA[3], x3.z, wa2); fma4(accA[3], x3.w, wa3);
    fma4(accB[0], x0.x, wb0); fma4(accB[0], x0.y, wb1); fma4(accB[0], x0.z, wb2); fma4(accB[0], x0.w, wb3);
    fma4(accB[1], x1.x, wb0); fma4(accB[1], x1.y, wb1); fma4(accB[1], x1.z, wb2); fma4(accB[1], x1.w, wb3);
    fma4(accB[2], x2.x, wb0); fma4(accB[2], x2.y, wb1); fma4(accB[2], x2.z, wb2); fma4(accB[2], x2.w, wb3);
    fma4(accB[3], x3.x, wb0); fma4(accB[3], x3.y, wb1); fma4(accB[3], x3.z, wb2); fma4(accB[3], x3.w, wb3);
  }
  float4 bv0 = *(const float4*)&b0[c0];
  float4 bv1 = *(const float4*)&b1[c0];
#pragma unroll
  for (int i = 0; i < 4; ++i) {
    if (r0 + i < rows) {
      size_t rb = (size_t)(base + r0 + i) * DD + c0;
      float4 o0 = accA[i]; add4(o0, bv0);
      float4 o1 = accB[i]; add4(o1, bv1);
      *(float4*)&out0[rb] = o0;
      *(float4*)&out1[rb] = o1;
    }
  }
}

// ---------------- bond pass 1: e_pre = (Ah[u]+Ah[v]+e@W1+b1+Cu[m])*norm ; BN stats ----------------
__global__ __launch_bounds__(BLK) void bond1_kernel(
    const float* __restrict__ e, int nrows, int ntiles,
    const float* __restrict__ W1, const float* __restrict__ b1,
    const float* __restrict__ Ah, const float* __restrict__ Cu,
    const int* __restrict__ bu, const int* __restrict__ bv, const int* __restrict__ b2m,
    const float* __restrict__ nrm,
    float* __restrict__ e_pre,
    float* __restrict__ ssum, float* __restrict__ ssq) {
  __shared__ __align__(16) float xs[TILE][DD + 4];
  __shared__ __align__(16) float wl[DD][DD];
  __shared__ int sbu[TILE], sbv[TILE], sbm[TILE];
  __shared__ float snb[TILE];
  __shared__ __align__(16) float red[16][DD];
  const int tid = threadIdx.x;
  const int tr = tid >> 4, tc = tid & 15, r0 = tr * 4, c0 = tc * 4;
  for (int l = tid; l < DD * DD; l += BLK) wl[l >> 6][l & 63] = W1[l];
  float4 bp = *(const float4*)&b1[c0];
  float4 lsum = make_float4(0.f, 0.f, 0.f, 0.f);
  float4 lsq  = make_float4(0.f, 0.f, 0.f, 0.f);
  for (int tile = blockIdx.x; tile < ntiles; tile += gridDim.x) {
    const int base = tile * TILE;
    int rows = nrows - base; if (rows > TILE) rows = TILE;
    __syncthreads();
    for (int l = tid; l < TILE * DD; l += BLK) {
      int r = l >> 6, c = l & 63;
      xs[r][c] = (r < rows) ? e[(size_t)(base + r) * DD + c] : 0.f;
    }
    if (tid < TILE) {
      bool v = tid < rows;
      int rb = base + tid;
      sbu[tid] = v ? bu[rb] : 0;
      sbv[tid] = v ? bv[rb] : 0;
      sbm[tid] = v ? b2m[rb] : 0;
      snb[tid] = v ? nrm[rb] : 0.f;
    }
    __syncthreads();
    float4 acc[4];
#pragma unroll
    for (int i = 0; i < 4; ++i) acc[i] = make_float4(0.f, 0.f, 0.f, 0.f);
    matmul_tile(xs, wl, r0, c0, acc);
#pragma unroll
    for (int i = 0; i < 4; ++i) {
      int r = r0 + i;
      if (r < rows) {
        int rb = base + r;
        float nb = snb[r];
        float4 ga = *(const float4*)&Ah[(size_t)sbu[r] * DD + c0];
        float4 gb = *(const float4*)&Ah[(size_t)sbv[r] * DD + c0];
        float4 gc = *(const float4*)&Cu[(size_t)sbm[r] * DD + c0];
        float4 o = acc[i];
        add4(o, bp); add4(o, ga); add4(o, gb); add4(o, gc);
        scale4(o, nb);
        add4(lsum, o); sqacc4(lsq, o);
        *(float4*)&e_pre[(size_t)rb * DD + c0] = o;
      }
    }
  }
  __syncthreads();
  *(float4*)&red[tr][c0] = lsum;
  __syncthreads();
  if (tid < DD) {
    float s = 0.f;
#pragma unroll
    for (int t = 0; t < 16; ++t) s += red[t][tid];
    atomicAdd(&ssum[tid], s);
  }
  __syncthreads();
  *(float4*)&red[tr][c0] = lsq;
  __syncthreads();
  if (tid < DD) {
    float s = 0.f;
#pragma unroll
    for (int t = 0; t < 16; ++t) s += red[t][tid];
    atomicAdd(&ssq[tid], s);
  }
}

// ---------------- BN finalize: scale/shift ----------------
__global__ void bnfinal_kernel(const float* __restrict__ ssum, const float* __restrict__ ssq,
                               const float* __restrict__ gamma, const float* __restrict__ beta,
                               float invN, float* __restrict__ scale, float* __restrict__ shift) {
  int j = threadIdx.x;
  float m = ssum[j] * invN;
  float v = ssq[j] * invN - m * m;
  float sc = gamma[j] * rsqrtf(v + 1e-5f);
  scale[j] = sc;
  shift[j] = beta[j] - m * sc;
}

// ---------------- bond pass 2: BN+ELU e (in place), sigmoid gate scatter, He matmul -> mol acc ----------------
__global__ __launch_bounds__(BLK) void bond2_kernel(
    float* __restrict__ e_io, int nrows,
    const float* __restrict__ scale, const float* __restrict__ shift,
    const float* __restrict__ Eh,
    const int* __restrict__ bu, const int* __restrict__ bv, const int* __restrict__ b2m,
    const float* __restrict__ W7, const float* __restrict__ b7,
    float* __restrict__ num, float* __restrict__ den, float* __restrict__ uaccb) {
  __shared__ __align__(16) float xs[TILE][DD + 4];
  __shared__ __align__(16) float wl[DD][DD];
  __shared__ int sbu[TILE], sbv[TILE], sbm[TILE];
  const int tid = threadIdx.x;
  const int base = blockIdx.x * TILE;
  int rows = nrows - base; if (rows > TILE) rows = TILE;
  for (int l = tid; l < DD * DD; l += BLK) wl[l >> 6][l & 63] = W7[l];
  if (tid < TILE) {
    bool v = tid < rows;
    int rb = base + tid;
    sbu[tid] = v ? bu[rb] : 0;
    sbv[tid] = v ? bv[rb] : 0;
    sbm[tid] = v ? b2m[rb] : 0;
  }
  __syncthreads();
  for (int l = tid; l < TILE * DD; l += BLK) {
    int r = l >> 6, c = l & 63;
    float en = 0.f;
    if (r < rows) {
      int rb = base + r;
      float xp = e_io[(size_t)rb * DD + c];
      float xn = xp * scale[c] + shift[c];
      en = elu_f(xn);
      e_io[(size_t)rb * DD + c] = en;
      float sg = 1.f / (1.f + expf(-en));
      int iu = sbu[r], iv = sbv[r];
      float ehv = Eh[(size_t)iv * DD + c];
      float ehu = Eh[(size_t)iu * DD + c];
      atomicAdd(&num[(size_t)iu * DD + c], sg * ehv);
      atomicAdd(&num[(size_t)iv * DD + c], sg * ehu);
      atomicAdd(&den[(size_t)iu * DD + c], sg);
      atomicAdd(&den[(size_t)iv * DD + c], sg);
    }
    xs[r][c] = en;
  }
  __syncthreads();
  const int tr = tid >> 4, tc = tid & 15, r0 = tr * 4, c0 = tc * 4;
  float4 acc[4];
#pragma unroll
  for (int i = 0; i < 4; ++i) acc[i] = make_float4(0.f, 0.f, 0.f, 0.f);
  matmul_tile(xs, wl, r0, c0, acc);
  float4 bp = *(const float4*)&b7[c0];
#pragma unroll
  for (int i = 0; i < 4; ++i) {
    int r = r0 + i;
    if (r < rows) {
      float* dst = &uaccb[(size_t)sbm[r] * DD + c0];
      atomicAdd(&dst[0], acc[i].x + bp.x);
      atomicAdd(&dst[1], acc[i].y + bp.y);
      atomicAdd(&dst[2], acc[i].z + bp.z);
      atomicAdd(&dst[3], acc[i].w + bp.w);
    }
  }
}

// ---------------- atom pass 1: h_pre = (h@W3+b3 + num/(den+eps) + Fu[m])*norm ; BN stats ----------------
__global__ __launch_bounds__(BLK) void atom1_kernel(
    const float* __restrict__ h, int nrows, int ntiles,
    const float* __restrict__ W3, const float* __restrict__ b3,
    const float* __restrict__ den, const float* __restrict__ Fu,
    const int* __restrict__ a2m, const float* __restrict__ nrm,
    float* __restrict__ hio,  // num in, h_pre out (same buffer)
    float* __restrict__ ssum, float* __restrict__ ssq) {
  __shared__ __align__(16) float xs[TILE][DD + 4];
  __shared__ __align__(16) float wl[DD][DD];
  __shared__ int sam[TILE];
  __shared__ float sna[TILE];
  __shared__ __align__(16) float red[16][DD];
  const int tid = threadIdx.x;
  const int tr = tid >> 4, tc = tid & 15, r0 = tr * 4, c0 = tc * 4;
  for (int l = tid; l < DD * DD; l += BLK) wl[l >> 6][l & 63] = W3[l];
  float4 bp = *(const float4*)&b3[c0];
  float4 lsum = make_float4(0.f, 0.f, 0.f, 0.f);
  float4 lsq  = make_float4(0.f, 0.f, 0.f, 0.f);
  for (int tile = blockIdx.x; tile < ntiles; tile += gridDim.x) {
    const int base = tile * TILE;
    int rows = nrows - base; if (rows > TILE) rows = TILE;
    __syncthreads();
    for (int l = tid; l < TILE * DD; l += BLK) {
      int r = l >> 6, c = l & 63;
      xs[r][c] = (r < rows) ? h[(size_t)(base + r) * DD + c] : 0.f;
    }
    if (tid < TILE) {
      bool v = tid < rows;
      int rb = base + tid;
      sam[tid] = v ? a2m[rb] : 0;
      sna[tid] = v ? nrm[rb] : 0.f;
    }
    __syncthreads();
    float4 acc[4];
#pragma unroll
    for (int i = 0; i < 4; ++i) acc[i] = make_float4(0.f, 0.f, 0.f, 0.f);
    matmul_tile(xs, wl, r0, c0, acc);
#pragma unroll
    for (int i = 0; i < 4; ++i) {
      int r = r0 + i;
      if (r < rows) {
        size_t rb = (size_t)(base + r) * DD + c0;
        float na = sna[r];
        float4 n4 = *(const float4*)&hio[rb];
        float4 d4 = *(const float4*)&den[rb];
        float4 f4 = *(const float4*)&Fu[(size_t)sam[r] * DD + c0];
        float4 o;
        o.x = (acc[i].x + bp.x + n4.x / (d4.x + 1e-6f) + f4.x) * na;
        o.y = (acc[i].y + bp.y + n4.y / (d4.y + 1e-6f) + f4.y) * na;
        o.z = (acc[i].z + bp.z + n4.z / (d4.z + 1e-6f) + f4.z) * na;
        o.w = (acc[i].w + bp.w + n4.w / (d4.w + 1e-6f) + f4.w) * na;
        add4(lsum, o); sqacc4(lsq, o);
        *(float4*)&hio[rb] = o;
      }
    }
  }
  __syncthreads();
  *(float4*)&red[tr][c0] = lsum;
  __syncthreads();
  if (tid < DD) {
    float s = 0.f;
#pragma unroll
    for (int t = 0; t < 16; ++t) s += red[t][tid];
    atomicAdd(&ssum[tid], s);
  }
  __syncthreads();
  *(float4*)&red[tr][c0] = lsq;
  __syncthreads();
  if (tid < DD) {
    float s = 0.f;
#pragma unroll
    for (int t = 0; t < 16; ++t) s += red[t][tid];
    atomicAdd(&ssq[tid], s);
  }
}

// ---------------- atom pass 2: BN+ELU h (in place), Gh matmul -> mol acc ----------------
__global__ __launch_bounds__(BLK) void atom2_kernel(
    float* __restrict__ hio, int nrows,
    const float* __restrict__ scale, const float* __restrict__ shift,
    const int* __restrict__ a2m,
    const float* __restrict__ W6, const float* __restrict__ b6,
    float* __restrict__ uacca) {
  __shared__ __align__(16) float xs[TILE][DD + 4];
  __shared__ __align__(16) float wl[DD][DD];
  __shared__ int sam[TILE];
  const int tid = threadIdx.x;
  const int base = blockIdx.x * TILE;
  int rows = nrows - base; if (rows > TILE) rows = TILE;
  for (int l = tid; l < DD * DD; l += BLK) wl[l >> 6][l & 63] = W6[l];
  if (tid < TILE) {
    sam[tid] = (tid < rows) ? a2m[base + tid] : 0;
  }
  __syncthreads();
  for (int l = tid; l < TILE * DD; l += BLK) {
    int r = l >> 6, c = l & 63;
    float hn = 0.f;
    if (r < rows) {
      size_t rb = (size_t)(base + r) * DD + c;
      float xp = hio[rb];
      float xn = xp * scale[c] + shift[c];
      hn = elu_f(xn);
      hio[rb] = hn;
    }
    xs[r][c] = hn;
  }
  __syncthreads();
  const int tr = tid >> 4, tc = tid & 15, r0 = tr * 4, c0 = tc * 4;
  float4 acc[4];
#pragma unroll
  for (int i = 0; i < 4; ++i) acc[i] = make_float4(0.f, 0.f, 0.f, 0.f);
  matmul_tile(xs, wl, r0, c0, acc);
  float4 bp = *(const float4*)&b6[c0];
#pragma unroll
  for (int i = 0; i < 4; ++i) {
    int r = r0 + i;
    if (r < rows) {
      float* dst = &uacca[(size_t)sam[r] * DD + c0];
      atomicAdd(&dst[0], acc[i].x + bp.x);
      atomicAdd(&dst[1], acc[i].y + bp.y);
      atomicAdd(&dst[2], acc[i].z + bp.z);
      atomicAdd(&dst[3], acc[i].w + bp.w);
    }
  }
}

// ---------------- global pass: u_pre = acc_a/cnt_a + acc_b/cnt_b + u@W8+b8 ; BN stats ----------------
__global__ __launch_bounds__(BLK) void global1_kernel(
    const float* __restrict__ u, int nrows,
    const float* __restrict__ W8, const float* __restrict__ b8,
    const float* __restrict__ uacca, const float* __restrict__ uaccb,
    const float* __restrict__ cnta, const float* __restrict__ cntb,
    float* __restrict__ upre,
    float* __restrict__ ssum, float* __restrict__ ssq) {
  __shared__ __align__(16) float xs[TILE][DD + 4];
  __shared__ __align__(16) float wl[DD][DD];
  __shared__ float sca[TILE], scb[TILE];
  __shared__ __align__(16) float red[16][DD];
  const int tid = threadIdx.x;
  const int base = blockIdx.x * TILE;
  int rows = nrows - base; if (rows > TILE) rows = TILE;
  for (int l = tid; l < DD * DD; l += BLK) wl[l >> 6][l & 63] = W8[l];
  for (int l = tid; l < TILE * DD; l += BLK) {
    int r = l >> 6, c = l & 63;
    xs[r][c] = (r < rows) ? u[(size_t)(base + r) * DD + c] : 0.f;
  }
  if (tid < TILE) {
    bool v = tid < rows;
    float ca = v ? cnta[base + tid] : 1.f;
    float cb = v ? cntb[base + tid] : 1.f;
    sca[tid] = ca < 1.f ? 1.f : ca;
    scb[tid] = cb < 1.f ? 1.f : cb;
  }
  __syncthreads();
  const int tr = tid >> 4, tc = tid & 15, r0 = tr * 4, c0 = tc * 4;
  float4 acc[4];
#pragma unroll
  for (int i = 0; i < 4; ++i) acc[i] = make_float4(0.f, 0.f, 0.f, 0.f);
  matmul_tile(xs, wl, r0, c0, acc);
  float4 bp = *(const float4*)&b8[c0];
  float4 lsum = make_float4(0.f, 0.f, 0.f, 0.f);
  float4 lsq  = make_float4(0.f, 0.f, 0.f, 0.f);
#pragma unroll
  for (int i = 0; i < 4; ++i) {
    int r = r0 + i;
    if (r < rows) {
      size_t rb = (size_t)(base + r) * DD + c0;
      float rca = 1.f / sca[r], rcb = 1.f / scb[r];
      float4 a4 = *(const float4*)&uacca[rb];
      float4 b4 = *(const float4*)&uaccb[rb];
      float4 o;
      o.x = a4.x * rca + b4.x * rcb + acc[i].x + bp.x;
      o.y = a4.y * rca + b4.y * rcb + acc[i].y + bp.y;
      o.z = a4.z * rca + b4.z * rcb + acc[i].z + bp.z;
      o.w = a4.w * rca + b4.w * rcb + acc[i].w + bp.w;
      add4(lsum, o); sqacc4(lsq, o);
      *(float4*)&upre[rb] = o;
    }
  }
  __syncthreads();
  *(float4*)&red[tr][c0] = lsum;
  __syncthreads();
  if (tid < DD) {
    float s = 0.f;
#pragma unroll
    for (int t = 0; t < 16; ++t) s += red[t][tid];
    atomicAdd(&ssum[tid], s);
  }
  __syncthreads();
  *(float4*)&red[tr][c0] = lsq;
  __syncthreads();
  if (tid < DD) {
    float s = 0.f;
#pragma unroll
    for (int t = 0; t < 16; ++t) s += red[t][tid];
    atomicAdd(&ssq[tid], s);
  }
}

// ---------------- final BN+ELU on u (in place) ----------------
__global__ void bn_elu_kernel(float* __restrict__ x, int n,
                              const float* __restrict__ scale, const float* __restrict__ shift) {
  int i = blockIdx.x * blockDim.x + threadIdx.x;
  if (i < n) {
    int c = i & 63;
    float v = x[i] * scale[c] + shift[c];
    x[i] = elu_f(v);
  }
}

extern "C" void kernel_launch(void* const* d_in, const int* in_sizes, int n_in,
                              void* d_out, int out_size, void* d_ws, size_t ws_size,
                              hipStream_t stream) {
  const float* h         = (const float*)d_in[0];
  const float* e         = (const float*)d_in[1];
  const float* u         = (const float*)d_in[2];
  const float* norm_atom = (const float*)d_in[3];
  const float* norm_bond = (const float*)d_in[4];
  const float* Ws        = (const float*)d_in[5];
  const float* bsarr     = (const float*)d_in[6];
  const float* bn_gamma  = (const float*)d_in[7];
  const float* bn_beta   = (const float*)d_in[8];
  const int* bond_u      = (const int*)d_in[9];
  const int* bond_v      = (const int*)d_in[10];
  const int* a2m         = (const int*)d_in[11];
  const int* b2m         = (const int*)d_in[12];

  const int NA = in_sizes[0] / DD;
  const int NB = in_sizes[1] / DD;
  const int NM = in_sizes[2] / DD;

  float* out_h = (float*)d_out;
  float* out_e = out_h + (size_t)NA * DD;
  float* out_u = out_e + (size_t)NB * DD;

  // workspace layout (~138 MB): Ah(=den after bond1) | Eh | Cu | Fu | uacca | uaccb | cnta | cntb | stats | bnparams
  float* f    = (float*)d_ws;
  float* Ah   = f;                         // NA*64, reused as den after bond pass 1
  float* den  = Ah;
  float* Eh   = Ah + (size_t)NA * DD;
  float* Cu   = Eh + (size_t)NA * DD;
  float* Fu   = Cu + (size_t)NM * DD;
  float* uacca = Fu + (size_t)NM * DD;
  float* uaccb = uacca + (size_t)NM * DD;
  float* cnta  = uaccb + (size_t)NM * DD;
  float* cntb  = cnta + NM;
  float* stats = cntb + NM;                 // 6*64
  float* sum_e = stats, *sq_e = stats + 64;
  float* sum_h = stats + 128, *sq_h = stats + 192;
  float* sum_u = stats + 256, *sq_u = stats + 320;
  float* bnp  = stats + 384;                // 6*64
  float* sc_e = bnp, *sh_e = bnp + 64;
  float* sc_h = bnp + 128, *sh_h = bnp + 192;
  float* sc_u = bnp + 256, *sh_u = bnp + 320;

  const float* W0 = Ws + 0 * 4096; const float* b0 = bsarr + 0 * 64;
  const float* W1 = Ws + 1 * 4096; const float* b1 = bsarr + 1 * 64;
  const float* W2 = Ws + 2 * 4096; const float* b2 = bsarr + 2 * 64;
  const float* W3 = Ws + 3 * 4096; const float* b3 = bsarr + 3 * 64;
  const float* W4 = Ws + 4 * 4096; const float* b4 = bsarr + 4 * 64;
  const float* W5 = Ws + 5 * 4096; const float* b5 = bsarr + 5 * 64;
  const float* W6 = Ws + 6 * 4096; const float* b6 = bsarr + 6 * 64;
  const float* W7 = Ws + 7 * 4096; const float* b7 = bsarr + 7 * 64;
  const float* W8 = Ws + 8 * 4096; const float* b8 = bsarr + 8 * 64;

  const int tiles_a = (NA + TILE - 1) / TILE;
  const int tiles_b = (NB + TILE - 1) / TILE;
  const int tiles_m = (NM + TILE - 1) / TILE;

  // zero accumulators: uacca, uaccb, cnta, cntb, stats
  size_t zcount = (size_t)NM * DD * 2 + (size_t)NM * 2 + 384;
  hipMemsetAsync(uacca, 0, zcount * sizeof(float), stream);

  {
    int n = NA + NB;
    cnt_kernel<<<(n + BLK - 1) / BLK, BLK, 0, stream>>>(a2m, NA, b2m, NB, cnta, cntb);
  }

  lin2_kernel<<<tiles_a, BLK, 0, stream>>>(h, NA, W0, b0, Ah, W4, b4, Eh);
  lin2_kernel<<<tiles_m, BLK, 0, stream>>>(u, NM, W2, b2, Cu, W5, b5, Fu);

  int nblk_b = tiles_b < 2048 ? tiles_b : 2048;
  bond1_kernel<<<nblk_b, BLK, 0, stream>>>(e, NB, tiles_b, W1, b1, Ah, Cu,
                                           bond_u, bond_v, b2m, norm_bond,
                                           out_e, sum_e, sq_e);
  bnfinal_kernel<<<1, 64, 0, stream>>>(sum_e, sq_e, bn_gamma + 0, bn_beta + 0,
                                       1.f / (float)NB, sc_e, sh_e);

  // den reuses Ah's region (Ah dead after bond1); num lives in out_h
  hipMemsetAsync(den, 0, (size_t)NA * DD * sizeof(float), stream);
  hipMemsetAsync(out_h, 0, (size_t)NA * DD * sizeof(float), stream);

  bond2_kernel<<<tiles_b, BLK, 0, stream>>>(out_e, NB, sc_e, sh_e, Eh,
                                            bond_u, bond_v, b2m, W7, b7,
                                            out_h, den, uaccb);

  int nblk_a = tiles_a < 2048 ? tiles_a : 2048;
  atom1_kernel<<<nblk_a, BLK, 0, stream>>>(h, NA, tiles_a, W3, b3, den, Fu,
                                           a2m, norm_atom, out_h, sum_h, sq_h);
  bnfinal_kernel<<<1, 64, 0, stream>>>(sum_h, sq_h, bn_gamma + 64, bn_beta + 64,
                                       1.f / (float)NA, sc_h, sh_h);

  atom2_kernel<<<tiles_a, BLK, 0, stream>>>(out_h, NA, sc_h, sh_h, a2m, W6, b6, uacca);

  global1_kernel<<<tiles_m, BLK, 0, stream>>>(u, NM, W8, b8, uacca, uaccb,
                                              cnta, cntb, out_u, sum_u, sq_u);
  bnfinal_kernel<<<1, 64, 0, stream>>>(sum_u, sq_u, bn_gamma + 128, bn_beta + 128,
                                       1.f / (float)NM, sc_u, sh_u);
  bn_elu_kernel<<<((size_t)NM * DD + BLK - 1) / BLK, BLK, 0, stream>>>(out_u, NM * DD, sc_u, sh_u);
}

// Round 3
// 1056.469 us; speedup vs baseline: 3.3109x; 1.0057x over previous
//
#include <hip/hip_runtime.h>
#include <cmath>

#define DD 64
#define TILE 64
#define BLK 256

__device__ __forceinline__ float elu_f(float x) {
  return x > 0.f ? x : expm1f(x);
}

__device__ __forceinline__ void fma4(float4& a, float s, const float4 b) {
  a.x = fmaf(s, b.x, a.x);
  a.y = fmaf(s, b.y, a.y);
  a.z = fmaf(s, b.z, a.z);
  a.w = fmaf(s, b.w, a.w);
}
__device__ __forceinline__ void add4(float4& a, const float4 b) {
  a.x += b.x; a.y += b.y; a.z += b.z; a.w += b.w;
}
__device__ __forceinline__ void sqacc4(float4& a, const float4 b) {
  a.x = fmaf(b.x, b.x, a.x);
  a.y = fmaf(b.y, b.y, a.y);
  a.z = fmaf(b.z, b.z, a.z);
  a.w = fmaf(b.w, b.w, a.w);
}
__device__ __forceinline__ void scale4(float4& a, float s) {
  a.x *= s; a.y *= s; a.z *= s; a.w *= s;
}

// single-weight 64x64 micro-kernel: acc[i] (i=0..3 rows r0+i) += xs @ wl (cols c0..c0+3)
__device__ __forceinline__ void matmul_tile(const float (*xs)[DD + 4], const float (*wl)[DD],
                                            int r0, int c0, float4 acc[4]) {
#pragma unroll 2
  for (int k0 = 0; k0 < DD; k0 += 4) {
    float4 x0 = *(const float4*)&xs[r0 + 0][k0];
    float4 x1 = *(const float4*)&xs[r0 + 1][k0];
    float4 x2 = *(const float4*)&xs[r0 + 2][k0];
    float4 x3 = *(const float4*)&xs[r0 + 3][k0];
    float4 w0 = *(const float4*)&wl[k0 + 0][c0];
    float4 w1 = *(const float4*)&wl[k0 + 1][c0];
    float4 w2 = *(const float4*)&wl[k0 + 2][c0];
    float4 w3 = *(const float4*)&wl[k0 + 3][c0];
    fma4(acc[0], x0.x, w0); fma4(acc[0], x0.y, w1); fma4(acc[0], x0.z, w2); fma4(acc[0], x0.w, w3);
    fma4(acc[1], x1.x, w0); fma4(acc[1], x1.y, w1); fma4(acc[1], x1.z, w2); fma4(acc[1], x1.w, w3);
    fma4(acc[2], x2.x, w0); fma4(acc[2], x2.y, w1); fma4(acc[2], x2.z, w2); fma4(acc[2], x2.w, w3);
    fma4(acc[3], x3.x, w0); fma4(acc[3], x3.y, w1); fma4(acc[3], x3.z, w2); fma4(acc[3], x3.w, w3);
  }
}

// ---------------- counts per molecule + atom degree ----------------
__global__ void cnt_kernel(const int* __restrict__ a2m, int na,
                           const int* __restrict__ b2m, int nb,
                           const int* __restrict__ bu, const int* __restrict__ bv,
                           float* __restrict__ cnta, float* __restrict__ cntb,
                           int* __restrict__ deg) {
  int i = blockIdx.x * blockDim.x + threadIdx.x;
  if (i < na) {
    atomicAdd(&cnta[a2m[i]], 1.f);
  } else if (i < na + nb) {
    int b = i - na;
    atomicAdd(&cntb[b2m[b]], 1.f);
    atomicAdd(&deg[bu[b]], 1);
    atomicAdd(&deg[bv[b]], 1);
  }
}

// ---------------- CSR segment allocation: start[a] via wave-scan + one atomic per wave ----------------
__global__ void seg_alloc_kernel(const int* __restrict__ deg, int na,
                                 int* __restrict__ start, int* __restrict__ gcount) {
  int i = blockIdx.x * blockDim.x + threadIdx.x;
  int lane = threadIdx.x & 63;
  int d = (i < na) ? deg[i] : 0;
  int pre = d;
#pragma unroll
  for (int off = 1; off < 64; off <<= 1) {
    int t = __shfl_up(pre, off, 64);
    if (lane >= off) pre += t;
  }
  int total = __shfl(pre, 63, 64);
  int excl = pre - d;
  int base = 0;
  if (lane == 63) base = atomicAdd(gcount, total);
  base = __shfl(base, 63, 64);
  if (i < na) start[i] = base + excl;
}

// ---------------- CSR fill: adj[pos] = {bond, other_atom} ----------------
__global__ void fill_kernel(const int* __restrict__ bu, const int* __restrict__ bv, int nb,
                            const int* __restrict__ start, int* __restrict__ cur,
                            int2* __restrict__ adj) {
  int b = blockIdx.x * blockDim.x + threadIdx.x;
  if (b < nb) {
    int a0 = bu[b], a1 = bv[b];
    int p = start[a0] + atomicAdd(&cur[a0], 1);
    adj[p] = make_int2(b, a1);
    int q = start[a1] + atomicAdd(&cur[a1], 1);
    adj[q] = make_int2(b, a0);
  }
}

// ---------------- dual linear: out0 = x@W0+b0, out1 = x@W1+b1 ----------------
__global__ __launch_bounds__(BLK) void lin2_kernel(
    const float* __restrict__ x, int nrows,
    const float* __restrict__ W0, const float* __restrict__ b0, float* __restrict__ out0,
    const float* __restrict__ W1, const float* __restrict__ b1, float* __restrict__ out1) {
  __shared__ __align__(16) float xs[TILE][DD + 4];
  __shared__ __align__(16) float w0[DD][DD];
  __shared__ __align__(16) float w1[DD][DD];
  const int tid = threadIdx.x;
  const int base = blockIdx.x * TILE;
  int rows = nrows - base; if (rows > TILE) rows = TILE;
  for (int l = tid; l < DD * DD; l += BLK) {
    int r = l >> 6, c = l & 63;
    xs[r][c] = (r < rows) ? x[(size_t)(base + r) * DD + c] : 0.f;
    w0[r][c] = W0[l];
    w1[r][c] = W1[l];
  }
  __syncthreads();
  const int tr = tid >> 4, tc = tid & 15;
  const int r0 = tr * 4, c0 = tc * 4;
  float4 accA[4], accB[4];
#pragma unroll
  for (int i = 0; i < 4; ++i) {
    accA[i] = make_float4(0.f, 0.f, 0.f, 0.f);
    accB[i] = make_float4(0.f, 0.f, 0.f, 0.f);
  }
#pragma unroll 1
  for (int k0 = 0; k0 < DD; k0 += 4) {
    float4 x0 = *(const float4*)&xs[r0 + 0][k0];
    float4 x1 = *(const float4*)&xs[r0 + 1][k0];
    float4 x2 = *(const float4*)&xs[r0 + 2][k0];
    float4 x3 = *(const float4*)&xs[r0 + 3][k0];
    float4 wa0 = *(const float4*)&w0[k0 + 0][c0];
    float4 wa1 = *(const float4*)&w0[k0 + 1][c0];
    float4 wa2 = *(const float4*)&w0[k0 + 2][c0];
    float4 wa3 = *(const float4*)&w0[k0 + 3][c0];
    float4 wb0 = *(const float4*)&w1[k0 + 0][c0];
    float4 wb1 = *(const float4*)&w1[k0 + 1][c0];
    float4 wb2 = *(const float4*)&w1[k0 + 2][c0];
    float4 wb3 = *(const float4*)&w1[k0 + 3][c0];
    fma4(accA[0], x0.x, wa0); fma4(accA[0], x0.y, wa1); fma4(accA[0], x0.z, wa2); fma4(accA[0], x0.w, wa3);
    fma4(accA[1], x1.x, wa0); fma4(accA[1], x1.y, wa1); fma4(accA[1], x1.z, wa2); fma4(accA[1], x1.w, wa3);
    fma4(accA[2], x2.x, wa0); fma4(accA[2], x2.y, wa1); fma4(accA[2], x2.z, wa2); fma4(accA[2], x2.w, wa3);
    fma4(accA[3], x3.x, wa0); fma4(accA[3], x3.y, wa1); fma4(accA[3], x3.z, wa2); fma4(accA[3], x3.w, wa3);
    fma4(accB[0], x0.x, wb0); fma4(accB[0], x0.y, wb1); fma4(accB[0], x0.z, wb2); fma4(accB[0], x0.w, wb3);
    fma4(accB[1], x1.x, wb0); fma4(accB[1], x1.y, wb1); fma4(accB[1], x1.z, wb2); fma4(accB[1], x1.w, wb3);
    fma4(accB[2], x2.x, wb0); fma4(accB[2], x2.y, wb1); fma4(accB[2], x2.z, wb2); fma4(accB[2], x2.w, wb3);
    fma4(accB[3], x3.x, wb0); fma4(accB[3], x3.y, wb1); fma4(accB[3], x3.z, wb2); fma4(accB[3], x3.w, wb3);
  }
  float4 bv0 = *(const float4*)&b0[c0];
  float4 bv1 = *(const float4*)&b1[c0];
#pragma unroll
  for (int i = 0; i < 4; ++i) {
    if (r0 + i < rows) {
      size_t rb = (size_t)(base + r0 + i) * DD + c0;
      float4 o0 = accA[i]; add4(o0, bv0);
      float4 o1 = accB[i]; add4(o1, bv1);
      *(float4*)&out0[rb] = o0;
      *(float4*)&out1[rb] = o1;
    }
  }
}

// ---------------- bond pass 1: e_pre = (Ah[u]+Ah[v]+e@W1+b1+Cu[m])*norm ; BN stats ----------------
__global__ __launch_bounds__(BLK) void bond1_kernel(
    const float* __restrict__ e, int nrows, int ntiles,
    const float* __restrict__ W1, const float* __restrict__ b1,
    const float* __restrict__ Ah, const float* __restrict__ Cu,
    const int* __restrict__ bu, const int* __restrict__ bv, const int* __restrict__ b2m,
    const float* __restrict__ nrm,
    float* __restrict__ e_pre,
    float* __restrict__ ssum, float* __restrict__ ssq) {
  __shared__ __align__(16) float xs[TILE][DD + 4];
  __shared__ __align__(16) float wl[DD][DD];
  __shared__ int sbu[TILE], sbv[TILE], sbm[TILE];
  __shared__ float snb[TILE];
  __shared__ __align__(16) float red[16][DD];
  const int tid = threadIdx.x;
  const int tr = tid >> 4, tc = tid & 15, r0 = tr * 4, c0 = tc * 4;
  for (int l = tid; l < DD * DD; l += BLK) wl[l >> 6][l & 63] = W1[l];
  float4 bp = *(const float4*)&b1[c0];
  float4 lsum = make_float4(0.f, 0.f, 0.f, 0.f);
  float4 lsq  = make_float4(0.f, 0.f, 0.f, 0.f);
  for (int tile = blockIdx.x; tile < ntiles; tile += gridDim.x) {
    const int base = tile * TILE;
    int rows = nrows - base; if (rows > TILE) rows = TILE;
    __syncthreads();
    for (int l = tid; l < TILE * DD; l += BLK) {
      int r = l >> 6, c = l & 63;
      xs[r][c] = (r < rows) ? e[(size_t)(base + r) * DD + c] : 0.f;
    }
    if (tid < TILE) {
      bool v = tid < rows;
      int rb = base + tid;
      sbu[tid] = v ? bu[rb] : 0;
      sbv[tid] = v ? bv[rb] : 0;
      sbm[tid] = v ? b2m[rb] : 0;
      snb[tid] = v ? nrm[rb] : 0.f;
    }
    __syncthreads();
    float4 acc[4];
#pragma unroll
    for (int i = 0; i < 4; ++i) acc[i] = make_float4(0.f, 0.f, 0.f, 0.f);
    matmul_tile(xs, wl, r0, c0, acc);
#pragma unroll
    for (int i = 0; i < 4; ++i) {
      int r = r0 + i;
      if (r < rows) {
        int rb = base + r;
        float nb = snb[r];
        float4 ga = *(const float4*)&Ah[(size_t)sbu[r] * DD + c0];
        float4 gb = *(const float4*)&Ah[(size_t)sbv[r] * DD + c0];
        float4 gc = *(const float4*)&Cu[(size_t)sbm[r] * DD + c0];
        float4 o = acc[i];
        add4(o, bp); add4(o, ga); add4(o, gb); add4(o, gc);
        scale4(o, nb);
        add4(lsum, o); sqacc4(lsq, o);
        *(float4*)&e_pre[(size_t)rb * DD + c0] = o;
      }
    }
  }
  __syncthreads();
  *(float4*)&red[tr][c0] = lsum;
  __syncthreads();
  if (tid < DD) {
    float s = 0.f;
#pragma unroll
    for (int t = 0; t < 16; ++t) s += red[t][tid];
    atomicAdd(&ssum[tid], s);
  }
  __syncthreads();
  *(float4*)&red[tr][c0] = lsq;
  __syncthreads();
  if (tid < DD) {
    float s = 0.f;
#pragma unroll
    for (int t = 0; t < 16; ++t) s += red[t][tid];
    atomicAdd(&ssq[tid], s);
  }
}

// ---------------- BN finalize: scale/shift ----------------
__global__ void bnfinal_kernel(const float* __restrict__ ssum, const float* __restrict__ ssq,
                               const float* __restrict__ gamma, const float* __restrict__ beta,
                               float invN, float* __restrict__ scale, float* __restrict__ shift) {
  int j = threadIdx.x;
  float m = ssum[j] * invN;
  float v = ssq[j] * invN - m * m;
  float sc = gamma[j] * rsqrtf(v + 1e-5f);
  scale[j] = sc;
  shift[j] = beta[j] - m * sc;
}

// ---------------- bond pass 2: BN+ELU e (in place), He matmul -> mol acc ----------------
__global__ __launch_bounds__(BLK) void bond2_kernel(
    float* __restrict__ e_io, int nrows,
    const float* __restrict__ scale, const float* __restrict__ shift,
    const int* __restrict__ b2m,
    const float* __restrict__ W7, const float* __restrict__ b7,
    float* __restrict__ uaccb) {
  __shared__ __align__(16) float xs[TILE][DD + 4];
  __shared__ __align__(16) float wl[DD][DD];
  __shared__ int sbm[TILE];
  const int tid = threadIdx.x;
  const int base = blockIdx.x * TILE;
  int rows = nrows - base; if (rows > TILE) rows = TILE;
  for (int l = tid; l < DD * DD; l += BLK) wl[l >> 6][l & 63] = W7[l];
  if (tid < TILE) {
    sbm[tid] = (tid < rows) ? b2m[base + tid] : 0;
  }
  __syncthreads();
  for (int l = tid; l < TILE * DD; l += BLK) {
    int r = l >> 6, c = l & 63;
    float en = 0.f;
    if (r < rows) {
      size_t rb = (size_t)(base + r) * DD + c;
      float xp = e_io[rb];
      float xn = xp * scale[c] + shift[c];
      en = elu_f(xn);
      e_io[rb] = en;
    }
    xs[r][c] = en;
  }
  __syncthreads();
  const int tr = tid >> 4, tc = tid & 15, r0 = tr * 4, c0 = tc * 4;
  float4 acc[4];
#pragma unroll
  for (int i = 0; i < 4; ++i) acc[i] = make_float4(0.f, 0.f, 0.f, 0.f);
  matmul_tile(xs, wl, r0, c0, acc);
  float4 bp = *(const float4*)&b7[c0];
#pragma unroll
  for (int i = 0; i < 4; ++i) {
    int r = r0 + i;
    if (r < rows) {
      float* dst = &uaccb[(size_t)sbm[r] * DD + c0];
      atomicAdd(&dst[0], acc[i].x + bp.x);
      atomicAdd(&dst[1], acc[i].y + bp.y);
      atomicAdd(&dst[2], acc[i].z + bp.z);
      atomicAdd(&dst[3], acc[i].w + bp.w);
    }
  }
}

// ---------------- pull aggregation: agg[a] = num/(den+eps), one wave per atom ----------------
__global__ __launch_bounds__(BLK) void agg_kernel(
    const float* __restrict__ e_act, const float* __restrict__ Eh,
    const int* __restrict__ start, const int* __restrict__ deg,
    const int2* __restrict__ adj, int na,
    float* __restrict__ aggout) {
  int wid = (int)((blockIdx.x * (unsigned)blockDim.x + threadIdx.x) >> 6);
  int lane = threadIdx.x & 63;
  if (wid >= na) return;
  int s = start[wid], d = deg[wid];
  float num = 0.f, den = 0.f;
  for (int k = 0; k < d; ++k) {
    int2 ent = adj[s + k];
    float ev = e_act[(size_t)ent.x * DD + lane];
    float sg = 1.f / (1.f + expf(-ev));
    float eh = Eh[(size_t)ent.y * DD + lane];
    num = fmaf(sg, eh, num);
    den += sg;
  }
  aggout[(size_t)wid * DD + lane] = num / (den + 1e-6f);
}

// ---------------- atom pass 1: h_pre = (h@W3+b3 + agg + Fu[m])*norm ; BN stats ----------------
__global__ __launch_bounds__(BLK) void atom1_kernel(
    const float* __restrict__ h, int nrows, int ntiles,
    const float* __restrict__ W3, const float* __restrict__ b3,
    const float* __restrict__ Fu,
    const int* __restrict__ a2m, const float* __restrict__ nrm,
    float* __restrict__ hio,  // agg in, h_pre out (same buffer)
    float* __restrict__ ssum, float* __restrict__ ssq) {
  __shared__ __align__(16) float xs[TILE][DD + 4];
  __shared__ __align__(16) float wl[DD][DD];
  __shared__ int sam[TILE];
  __shared__ float sna[TILE];
  __shared__ __align__(16) float red[16][DD];
  const int tid = threadIdx.x;
  const int tr = tid >> 4, tc = tid & 15, r0 = tr * 4, c0 = tc * 4;
  for (int l = tid; l < DD * DD; l += BLK) wl[l >> 6][l & 63] = W3[l];
  float4 bp = *(const float4*)&b3[c0];
  float4 lsum = make_float4(0.f, 0.f, 0.f, 0.f);
  float4 lsq  = make_float4(0.f, 0.f, 0.f, 0.f);
  for (int tile = blockIdx.x; tile < ntiles; tile += gridDim.x) {
    const int base = tile * TILE;
    int rows = nrows - base; if (rows > TILE) rows = TILE;
    __syncthreads();
    for (int l = tid; l < TILE * DD; l += BLK) {
      int r = l >> 6, c = l & 63;
      xs[r][c] = (r < rows) ? h[(size_t)(base + r) * DD + c] : 0.f;
    }
    if (tid < TILE) {
      bool v = tid < rows;
      int rb = base + tid;
      sam[tid] = v ? a2m[rb] : 0;
      sna[tid] = v ? nrm[rb] : 0.f;
    }
    __syncthreads();
    float4 acc[4];
#pragma unroll
    for (int i = 0; i < 4; ++i) acc[i] = make_float4(0.f, 0.f, 0.f, 0.f);
    matmul_tile(xs, wl, r0, c0, acc);
#pragma unroll
    for (int i = 0; i < 4; ++i) {
      int r = r0 + i;
      if (r < rows) {
        size_t rb = (size_t)(base + r) * DD + c0;
        float na = sna[r];
        float4 g4 = *(const float4*)&hio[rb];
        float4 f4 = *(const float4*)&Fu[(size_t)sam[r] * DD + c0];
        float4 o;
        o.x = (acc[i].x + bp.x + g4.x + f4.x) * na;
        o.y = (acc[i].y + bp.y + g4.y + f4.y) * na;
        o.z = (acc[i].z + bp.z + g4.z + f4.z) * na;
        o.w = (acc[i].w + bp.w + g4.w + f4.w) * na;
        add4(lsum, o); sqacc4(lsq, o);
        *(float4*)&hio[rb] = o;
      }
    }
  }
  __syncthreads();
  *(float4*)&red[tr][c0] = lsum;
  __syncthreads();
  if (tid < DD) {
    float s = 0.f;
#pragma unroll
    for (int t = 0; t < 16; ++t) s += red[t][tid];
    atomicAdd(&ssum[tid], s);
  }
  __syncthreads();
  *(float4*)&red[tr][c0] = lsq;
  __syncthreads();
  if (tid < DD) {
    float s = 0.f;
#pragma unroll
    for (int t = 0; t < 16; ++t) s += red[t][tid];
    atomicAdd(&ssq[tid], s);
  }
}

// ---------------- atom pass 2: BN+ELU h (in place), Gh matmul -> mol acc ----------------
__global__ __launch_bounds__(BLK) void atom2_kernel(
    float* __restrict__ hio, int nrows,
    const float* __restrict__ scale, const float* __restrict__ shift,
    const int* __restrict__ a2m,
    const float* __restrict__ W6, const float* __restrict__ b6,
    float* __restrict__ uacca) {
  __shared__ __align__(16) float xs[TILE][DD + 4];
  __shared__ __align__(16) float wl[DD][DD];
  __shared__ int sam[TILE];
  const int tid = threadIdx.x;
  const int base = blockIdx.x * TILE;
  int rows = nrows - base; if (rows > TILE) rows = TILE;
  for (int l = tid; l < DD * DD; l += BLK) wl[l >> 6][l & 63] = W6[l];
  if (tid < TILE) {
    sam[tid] = (tid < rows) ? a2m[base + tid] : 0;
  }
  __syncthreads();
  for (int l = tid; l < TILE * DD; l += BLK) {
    int r = l >> 6, c = l & 63;
    float hn = 0.f;
    if (r < rows) {
      size_t rb = (size_t)(base + r) * DD + c;
      float xp = hio[rb];
      float xn = xp * scale[c] + shift[c];
      hn = elu_f(xn);
      hio[rb] = hn;
    }
    xs[r][c] = hn;
  }
  __syncthreads();
  const int tr = tid >> 4, tc = tid & 15, r0 = tr * 4, c0 = tc * 4;
  float4 acc[4];
#pragma unroll
  for (int i = 0; i < 4; ++i) acc[i] = make_float4(0.f, 0.f, 0.f, 0.f);
  matmul_tile(xs, wl, r0, c0, acc);
  float4 bp = *(const float4*)&b6[c0];
#pragma unroll
  for (int i = 0; i < 4; ++i) {
    int r = r0 + i;
    if (r < rows) {
      float* dst = &uacca[(size_t)sam[r] * DD + c0];
      atomicAdd(&dst[0], acc[i].x + bp.x);
      atomicAdd(&dst[1], acc[i].y + bp.y);
      atomicAdd(&dst[2], acc[i].z + bp.z);
      atomicAdd(&dst[3], acc[i].w + bp.w);
    }
  }
}

// ---------------- global pass: u_pre = acc_a/cnt_a + acc_b/cnt_b + u@W8+b8 ; BN stats ----------------
__global__ __launch_bounds__(BLK) void global1_kernel(
    const float* __restrict__ u, int nrows,
    const float* __restrict__ W8, const float* __restrict__ b8,
    const float* __restrict__ uacca, const float* __restrict__ uaccb,
    const float* __restrict__ cnta, const float* __restrict__ cntb,
    float* __restrict__ upre,
    float* __restrict__ ssum, float* __restrict__ ssq) {
  __shared__ __align__(16) float xs[TILE][DD + 4];
  __shared__ __align__(16) float wl[DD][DD];
  __shared__ float sca[TILE], scb[TILE];
  __shared__ __align__(16) float red[16][DD];
  const int tid = threadIdx.x;
  const int base = blockIdx.x * TILE;
  int rows = nrows - base; if (rows > TILE) rows = TILE;
  for (int l = tid; l < DD * DD; l += BLK) wl[l >> 6][l & 63] = W8[l];
  for (int l = tid; l < TILE * DD; l += BLK) {
    int r = l >> 6, c = l & 63;
    xs[r][c] = (r < rows) ? u[(size_t)(base + r) * DD + c] : 0.f;
  }
  if (tid < TILE) {
    bool v = tid < rows;
    float ca = v ? cnta[base + tid] : 1.f;
    float cb = v ? cntb[base + tid] : 1.f;
    sca[tid] = ca < 1.f ? 1.f : ca;
    scb[tid] = cb < 1.f ? 1.f : cb;
  }
  __syncthreads();
  const int tr = tid >> 4, tc = tid & 15, r0 = tr * 4, c0 = tc * 4;
  float4 acc[4];
#pragma unroll
  for (int i = 0; i < 4; ++i) acc[i] = make_float4(0.f, 0.f, 0.f, 0.f);
  matmul_tile(xs, wl, r0, c0, acc);
  float4 bp = *(const float4*)&b8[c0];
  float4 lsum = make_float4(0.f, 0.f, 0.f, 0.f);
  float4 lsq  = make_float4(0.f, 0.f, 0.f, 0.f);
#pragma unroll
  for (int i = 0; i < 4; ++i) {
    int r = r0 + i;
    if (r < rows) {
      size_t rb = (size_t)(base + r) * DD + c0;
      float rca = 1.f / sca[r], rcb = 1.f / scb[r];
      float4 a4 = *(const float4*)&uacca[rb];
      float4 b4 = *(const float4*)&uaccb[rb];
      float4 o;
      o.x = a4.x * rca + b4.x * rcb + acc[i].x + bp.x;
      o.y = a4.y * rca + b4.y * rcb + acc[i].y + bp.y;
      o.z = a4.z * rca + b4.z * rcb + acc[i].z + bp.z;
      o.w = a4.w * rca + b4.w * rcb + acc[i].w + bp.w;
      add4(lsum, o); sqacc4(lsq, o);
      *(float4*)&upre[rb] = o;
    }
  }
  __syncthreads();
  *(float4*)&red[tr][c0] = lsum;
  __syncthreads();
  if (tid < DD) {
    float s = 0.f;
#pragma unroll
    for (int t = 0; t < 16; ++t) s += red[t][tid];
    atomicAdd(&ssum[tid], s);
  }
  __syncthreads();
  *(float4*)&red[tr][c0] = lsq;
  __syncthreads();
  if (tid < DD) {
    float s = 0.f;
#pragma unroll
    for (int t = 0; t < 16; ++t) s += red[t][tid];
    atomicAdd(&ssq[tid], s);
  }
}

// ---------------- final BN+ELU on u (in place) ----------------
__global__ void bn_elu_kernel(float* __restrict__ x, int n,
                              const float* __restrict__ scale, const float* __restrict__ shift) {
  int i = blockIdx.x * blockDim.x + threadIdx.x;
  if (i < n) {
    int c = i & 63;
    float v = x[i] * scale[c] + shift[c];
    x[i] = elu_f(v);
  }
}

extern "C" void kernel_launch(void* const* d_in, const int* in_sizes, int n_in,
                              void* d_out, int out_size, void* d_ws, size_t ws_size,
                              hipStream_t stream) {
  const float* h         = (const float*)d_in[0];
  const float* e         = (const float*)d_in[1];
  const float* u         = (const float*)d_in[2];
  const float* norm_atom = (const float*)d_in[3];
  const float* norm_bond = (const float*)d_in[4];
  const float* Ws        = (const float*)d_in[5];
  const float* bsarr     = (const float*)d_in[6];
  const float* bn_gamma  = (const float*)d_in[7];
  const float* bn_beta   = (const float*)d_in[8];
  const int* bond_u      = (const int*)d_in[9];
  const int* bond_v      = (const int*)d_in[10];
  const int* a2m         = (const int*)d_in[11];
  const int* b2m         = (const int*)d_in[12];

  const int NA = in_sizes[0] / DD;
  const int NB = in_sizes[1] / DD;
  const int NM = in_sizes[2] / DD;

  float* out_h = (float*)d_out;
  float* out_e = out_h + (size_t)NA * DD;
  float* out_u = out_e + (size_t)NB * DD;

  // workspace layout (~145 MB):
  // Ah | Eh | Cu | Fu | uacca | uaccb | cnta | cntb | stats(384) | deg | cur | gcount(2) | bnp(384) | start | adj
  float* f    = (float*)d_ws;
  float* Ah   = f;
  float* Eh   = Ah + (size_t)NA * DD;
  float* Cu   = Eh + (size_t)NA * DD;
  float* Fu   = Cu + (size_t)NM * DD;
  float* uacca = Fu + (size_t)NM * DD;
  float* uaccb = uacca + (size_t)NM * DD;
  float* cnta  = uaccb + (size_t)NM * DD;
  float* cntb  = cnta + NM;
  float* stats = cntb + NM;                 // 6*64
  float* sum_e = stats, *sq_e = stats + 64;
  float* sum_h = stats + 128, *sq_h = stats + 192;
  float* sum_u = stats + 256, *sq_u = stats + 320;
  int* deg    = (int*)(stats + 384);        // NA
  int* cur    = deg + NA;                   // NA
  int* gcount = cur + NA;                   // 2 (pad for alignment)
  float* bnp  = (float*)(gcount + 2);       // 6*64
  float* sc_e = bnp, *sh_e = bnp + 64;
  float* sc_h = bnp + 128, *sh_h = bnp + 192;
  float* sc_u = bnp + 256, *sh_u = bnp + 320;
  int* start  = (int*)(bnp + 384);          // NA
  int2* adj   = (int2*)(start + NA);        // 2*NB entries (8B each)

  const float* W0 = Ws + 0 * 4096; const float* b0 = bsarr + 0 * 64;
  const float* W1 = Ws + 1 * 4096; const float* b1 = bsarr + 1 * 64;
  const float* W2 = Ws + 2 * 4096; const float* b2 = bsarr + 2 * 64;
  const float* W3 = Ws + 3 * 4096; const float* b3 = bsarr + 3 * 64;
  const float* W4 = Ws + 4 * 4096; const float* b4 = bsarr + 4 * 64;
  const float* W5 = Ws + 5 * 4096; const float* b5 = bsarr + 5 * 64;
  const float* W6 = Ws + 6 * 4096; const float* b6 = bsarr + 6 * 64;
  const float* W7 = Ws + 7 * 4096; const float* b7 = bsarr + 7 * 64;
  const float* W8 = Ws + 8 * 4096; const float* b8 = bsarr + 8 * 64;

  const int tiles_a = (NA + TILE - 1) / TILE;
  const int tiles_b = (NB + TILE - 1) / TILE;
  const int tiles_m = (NM + TILE - 1) / TILE;

  // zero region: uacca .. gcount (contiguous)
  size_t zbytes = ((size_t)NM * DD * 2 + (size_t)NM * 2 + 384) * sizeof(float)
                + ((size_t)NA * 2 + 2) * sizeof(int);
  hipMemsetAsync(uacca, 0, zbytes, stream);

  // counts + degrees
  {
    int n = NA + NB;
    cnt_kernel<<<(n + BLK - 1) / BLK, BLK, 0, stream>>>(a2m, NA, b2m, NB,
                                                        bond_u, bond_v, cnta, cntb, deg);
  }
  // CSR build
  seg_alloc_kernel<<<(NA + BLK - 1) / BLK, BLK, 0, stream>>>(deg, NA, start, gcount);
  fill_kernel<<<(NB + BLK - 1) / BLK, BLK, 0, stream>>>(bond_u, bond_v, NB, start, cur, adj);

  lin2_kernel<<<tiles_a, BLK, 0, stream>>>(h, NA, W0, b0, Ah, W4, b4, Eh);
  lin2_kernel<<<tiles_m, BLK, 0, stream>>>(u, NM, W2, b2, Cu, W5, b5, Fu);

  int nblk_b = tiles_b < 2048 ? tiles_b : 2048;
  bond1_kernel<<<nblk_b, BLK, 0, stream>>>(e, NB, tiles_b, W1, b1, Ah, Cu,
                                           bond_u, bond_v, b2m, norm_bond,
                                           out_e, sum_e, sq_e);
  bnfinal_kernel<<<1, 64, 0, stream>>>(sum_e, sq_e, bn_gamma + 0, bn_beta + 0,
                                       1.f / (float)NB, sc_e, sh_e);

  bond2_kernel<<<tiles_b, BLK, 0, stream>>>(out_e, NB, sc_e, sh_e,
                                            b2m, W7, b7, uaccb);

  // pull aggregation: one wave per atom -> out_h holds num/(den+eps)
  agg_kernel<<<(NA + 3) / 4, BLK, 0, stream>>>(out_e, Eh, start, deg, adj, NA, out_h);

  int nblk_a = tiles_a < 2048 ? tiles_a : 2048;
  atom1_kernel<<<nblk_a, BLK, 0, stream>>>(h, NA, tiles_a, W3, b3, Fu,
                                           a2m, norm_atom, out_h, sum_h, sq_h);
  bnfinal_kernel<<<1, 64, 0, stream>>>(sum_h, sq_h, bn_gamma + 64, bn_beta + 64,
                                       1.f / (float)NA, sc_h, sh_h);

  atom2_kernel<<<tiles_a, BLK, 0, stream>>>(out_h, NA, sc_h, sh_h, a2m, W6, b6, uacca);

  global1_kernel<<<tiles_m, BLK, 0, stream>>>(u, NM, W8, b8, uacca, uaccb,
                                              cnta, cntb, out_u, sum_u, sq_u);
  bnfinal_kernel<<<1, 64, 0, stream>>>(sum_u, sq_u, bn_gamma + 128, bn_beta + 128,
                                       1.f / (float)NM, sc_u, sh_u);
  bn_elu_kernel<<<((size_t)NM * DD + BLK - 1) / BLK, BLK, 0, stream>>>(out_u, NM * DD, sc_u, sh_u);
}

// Round 4
// 742.988 us; speedup vs baseline: 4.7078x; 1.4219x over previous
//
#include <hip/hip_runtime.h>
#include <cmath>

#define DD 64
#define TILE 64
#define BLK 256

__device__ __forceinline__ float elu_f(float x) {
  return x > 0.f ? x : expm1f(x);
}

__device__ __forceinline__ void fma4(float4& a, float s, const float4 b) {
  a.x = fmaf(s, b.x, a.x);
  a.y = fmaf(s, b.y, a.y);
  a.z = fmaf(s, b.z, a.z);
  a.w = fmaf(s, b.w, a.w);
}
__device__ __forceinline__ void add4(float4& a, const float4 b) {
  a.x += b.x; a.y += b.y; a.z += b.z; a.w += b.w;
}
__device__ __forceinline__ void sqacc4(float4& a, const float4 b) {
  a.x = fmaf(b.x, b.x, a.x);
  a.y = fmaf(b.y, b.y, a.y);
  a.z = fmaf(b.z, b.z, a.z);
  a.w = fmaf(b.w, b.w, a.w);
}
__device__ __forceinline__ void scale4(float4& a, float s) {
  a.x *= s; a.y *= s; a.z *= s; a.w *= s;
}

// single-weight 64x64 micro-kernel: acc[i] (rows r0..r0+3) += xs @ wl (cols c0..c0+3)
__device__ __forceinline__ void matmul_tile(const float (*xs)[DD + 4], const float (*wl)[DD],
                                            int r0, int c0, float4 acc[4]) {
#pragma unroll 2
  for (int k0 = 0; k0 < DD; k0 += 4) {
    float4 x0 = *(const float4*)&xs[r0 + 0][k0];
    float4 x1 = *(const float4*)&xs[r0 + 1][k0];
    float4 x2 = *(const float4*)&xs[r0 + 2][k0];
    float4 x3 = *(const float4*)&xs[r0 + 3][k0];
    float4 w0 = *(const float4*)&wl[k0 + 0][c0];
    float4 w1 = *(const float4*)&wl[k0 + 1][c0];
    float4 w2 = *(const float4*)&wl[k0 + 2][c0];
    float4 w3 = *(const float4*)&wl[k0 + 3][c0];
    fma4(acc[0], x0.x, w0); fma4(acc[0], x0.y, w1); fma4(acc[0], x0.z, w2); fma4(acc[0], x0.w, w3);
    fma4(acc[1], x1.x, w0); fma4(acc[1], x1.y, w1); fma4(acc[1], x1.z, w2); fma4(acc[1], x1.w, w3);
    fma4(acc[2], x2.x, w0); fma4(acc[2], x2.y, w1); fma4(acc[2], x2.z, w2); fma4(acc[2], x2.w, w3);
    fma4(acc[3], x3.x, w0); fma4(acc[3], x3.y, w1); fma4(acc[3], x3.z, w2); fma4(acc[3], x3.w, w3);
  }
}

// ---------------- counts (int) per molecule + atom degree ----------------
__global__ void cnt_kernel(const int* __restrict__ a2m, int na,
                           const int* __restrict__ b2m, int nb,
                           const int* __restrict__ bu, const int* __restrict__ bv,
                           int* __restrict__ cnta_i, int* __restrict__ cntb_i,
                           int* __restrict__ deg) {
  int i = blockIdx.x * blockDim.x + threadIdx.x;
  if (i < na) {
    atomicAdd(&cnta_i[a2m[i]], 1);
  } else if (i < na + nb) {
    int b = i - na;
    atomicAdd(&cntb_i[b2m[b]], 1);
    atomicAdd(&deg[bu[b]], 1);
    atomicAdd(&deg[bv[b]], 1);
  }
}

// ---------------- CSR segment allocation via wave-scan + one atomic per wave ----------------
__global__ void seg_alloc_kernel(const int* __restrict__ deg, int n,
                                 int* __restrict__ start, int* __restrict__ gcount) {
  int i = blockIdx.x * blockDim.x + threadIdx.x;
  int lane = threadIdx.x & 63;
  int d = (i < n) ? deg[i] : 0;
  int pre = d;
#pragma unroll
  for (int off = 1; off < 64; off <<= 1) {
    int t = __shfl_up(pre, off, 64);
    if (lane >= off) pre += t;
  }
  int total = __shfl(pre, 63, 64);
  int excl = pre - d;
  int base = 0;
  if (lane == 63) base = atomicAdd(gcount, total);
  base = __shfl(base, 63, 64);
  if (i < n) start[i] = base + excl;
}

// ---------------- atom adjacency fill: adj[pos] = {bond, other_atom} ----------------
__global__ void fill_kernel(const int* __restrict__ bu, const int* __restrict__ bv, int nb,
                            const int* __restrict__ start, int* __restrict__ cur,
                            int2* __restrict__ adj) {
  int b = blockIdx.x * blockDim.x + threadIdx.x;
  if (b < nb) {
    int a0 = bu[b], a1 = bv[b];
    int p = start[a0] + atomicAdd(&cur[a0], 1);
    adj[p] = make_int2(b, a1);
    int q = start[a1] + atomicAdd(&cur[a1], 1);
    adj[q] = make_int2(b, a0);
  }
}

// ---------------- mol member lists fill ----------------
__global__ void fill_mol_kernel(const int* __restrict__ a2m, int na,
                                const int* __restrict__ b2m, int nb,
                                const int* __restrict__ start_ma, int* __restrict__ cur_ma,
                                int* __restrict__ lista,
                                const int* __restrict__ start_mb, int* __restrict__ cur_mb,
                                int* __restrict__ listb) {
  int i = blockIdx.x * blockDim.x + threadIdx.x;
  if (i < na) {
    int m = a2m[i];
    lista[start_ma[m] + atomicAdd(&cur_ma[m], 1)] = i;
  } else if (i < na + nb) {
    int b = i - na;
    int m = b2m[b];
    listb[start_mb[m] + atomicAdd(&cur_mb[m], 1)] = b;
  }
}

// ---------------- dual linear: out0 = x@W0+b0, out1 = x@W1+b1 ----------------
__global__ __launch_bounds__(BLK) void lin2_kernel(
    const float* __restrict__ x, int nrows,
    const float* __restrict__ W0, const float* __restrict__ b0, float* __restrict__ out0,
    const float* __restrict__ W1, const float* __restrict__ b1, float* __restrict__ out1) {
  __shared__ __align__(16) float xs[TILE][DD + 4];
  __shared__ __align__(16) float w0[DD][DD];
  __shared__ __align__(16) float w1[DD][DD];
  const int tid = threadIdx.x;
  const int base = blockIdx.x * TILE;
  int rows = nrows - base; if (rows > TILE) rows = TILE;
  for (int l = tid; l < DD * DD; l += BLK) {
    int r = l >> 6, c = l & 63;
    xs[r][c] = (r < rows) ? x[(size_t)(base + r) * DD + c] : 0.f;
    w0[r][c] = W0[l];
    w1[r][c] = W1[l];
  }
  __syncthreads();
  const int tr = tid >> 4, tc = tid & 15;
  const int r0 = tr * 4, c0 = tc * 4;
  float4 accA[4], accB[4];
#pragma unroll
  for (int i = 0; i < 4; ++i) {
    accA[i] = make_float4(0.f, 0.f, 0.f, 0.f);
    accB[i] = make_float4(0.f, 0.f, 0.f, 0.f);
  }
#pragma unroll 1
  for (int k0 = 0; k0 < DD; k0 += 4) {
    float4 x0 = *(const float4*)&xs[r0 + 0][k0];
    float4 x1 = *(const float4*)&xs[r0 + 1][k0];
    float4 x2 = *(const float4*)&xs[r0 + 2][k0];
    float4 x3 = *(const float4*)&xs[r0 + 3][k0];
    float4 wa0 = *(const float4*)&w0[k0 + 0][c0];
    float4 wa1 = *(const float4*)&w0[k0 + 1][c0];
    float4 wa2 = *(const float4*)&w0[k0 + 2][c0];
    float4 wa3 = *(const float4*)&w0[k0 + 3][c0];
    float4 wb0 = *(const float4*)&w1[k0 + 0][c0];
    float4 wb1 = *(const float4*)&w1[k0 + 1][c0];
    float4 wb2 = *(const float4*)&w1[k0 + 2][c0];
    float4 wb3 = *(const float4*)&w1[k0 + 3][c0];
    fma4(accA[0], x0.x, wa0); fma4(accA[0], x0.y, wa1); fma4(accA[0], x0.z, wa2); fma4(accA[0], x0.w, wa3);
    fma4(accA[1], x1.x, wa0); fma4(accA[1], x1.y, wa1); fma4(accA[1], x1.z, wa2); fma4(accA[1], x1.w, wa3);
    fma4(accA[2], x2.x, wa0); fma4(accA[2], x2.y, wa1); fma4(accA[2], x2.z, wa2); fma4(accA[2], x2.w, wa3);
    fma4(accA[3], x3.x, wa0); fma4(accA[3], x3.y, wa1); fma4(accA[3], x3.z, wa2); fma4(accA[3], x3.w, wa3);
    fma4(accB[0], x0.x, wb0); fma4(accB[0], x0.y, wb1); fma4(accB[0], x0.z, wb2); fma4(accB[0], x0.w, wb3);
    fma4(accB[1], x1.x, wb0); fma4(accB[1], x1.y, wb1); fma4(accB[1], x1.z, wb2); fma4(accB[1], x1.w, wb3);
    fma4(accB[2], x2.x, wb0); fma4(accB[2], x2.y, wb1); fma4(accB[2], x2.z, wb2); fma4(accB[2], x2.w, wb3);
    fma4(accB[3], x3.x, wb0); fma4(accB[3], x3.y, wb1); fma4(accB[3], x3.z, wb2); fma4(accB[3], x3.w, wb3);
  }
  float4 bv0 = *(const float4*)&b0[c0];
  float4 bv1 = *(const float4*)&b1[c0];
#pragma unroll
  for (int i = 0; i < 4; ++i) {
    if (r0 + i < rows) {
      size_t rb = (size_t)(base + r0 + i) * DD + c0;
      float4 o0 = accA[i]; add4(o0, bv0);
      float4 o1 = accB[i]; add4(o1, bv1);
      *(float4*)&out0[rb] = o0;
      *(float4*)&out1[rb] = o1;
    }
  }
}

// ---------------- bond pass 1: e_pre = (Ah[u]+Ah[v]+e@W1+b1+Cu[m])*norm ; BN stats ----------------
__global__ __launch_bounds__(BLK) void bond1_kernel(
    const float* __restrict__ e, int nrows, int ntiles,
    const float* __restrict__ W1, const float* __restrict__ b1,
    const float* __restrict__ Ah, const float* __restrict__ Cu,
    const int* __restrict__ bu, const int* __restrict__ bv, const int* __restrict__ b2m,
    const float* __restrict__ nrm,
    float* __restrict__ e_pre,
    float* __restrict__ ssum, float* __restrict__ ssq) {
  __shared__ __align__(16) float xs[TILE][DD + 4];
  __shared__ __align__(16) float wl[DD][DD];
  __shared__ int sbu[TILE], sbv[TILE], sbm[TILE];
  __shared__ float snb[TILE];
  __shared__ __align__(16) float red[16][DD];
  const int tid = threadIdx.x;
  const int tr = tid >> 4, tc = tid & 15, r0 = tr * 4, c0 = tc * 4;
  for (int l = tid; l < DD * DD; l += BLK) wl[l >> 6][l & 63] = W1[l];
  float4 bp = *(const float4*)&b1[c0];
  float4 lsum = make_float4(0.f, 0.f, 0.f, 0.f);
  float4 lsq  = make_float4(0.f, 0.f, 0.f, 0.f);
  for (int tile = blockIdx.x; tile < ntiles; tile += gridDim.x) {
    const int base = tile * TILE;
    int rows = nrows - base; if (rows > TILE) rows = TILE;
    __syncthreads();
    for (int l = tid; l < TILE * DD; l += BLK) {
      int r = l >> 6, c = l & 63;
      xs[r][c] = (r < rows) ? e[(size_t)(base + r) * DD + c] : 0.f;
    }
    if (tid < TILE) {
      bool v = tid < rows;
      int rb = base + tid;
      sbu[tid] = v ? bu[rb] : 0;
      sbv[tid] = v ? bv[rb] : 0;
      sbm[tid] = v ? b2m[rb] : 0;
      snb[tid] = v ? nrm[rb] : 0.f;
    }
    __syncthreads();
    float4 acc[4];
#pragma unroll
    for (int i = 0; i < 4; ++i) acc[i] = make_float4(0.f, 0.f, 0.f, 0.f);
    matmul_tile(xs, wl, r0, c0, acc);
#pragma unroll
    for (int i = 0; i < 4; ++i) {
      int r = r0 + i;
      if (r < rows) {
        int rb = base + r;
        float nb = snb[r];
        float4 ga = *(const float4*)&Ah[(size_t)sbu[r] * DD + c0];
        float4 gb = *(const float4*)&Ah[(size_t)sbv[r] * DD + c0];
        float4 gc = *(const float4*)&Cu[(size_t)sbm[r] * DD + c0];
        float4 o = acc[i];
        add4(o, bp); add4(o, ga); add4(o, gb); add4(o, gc);
        scale4(o, nb);
        add4(lsum, o); sqacc4(lsq, o);
        *(float4*)&e_pre[(size_t)rb * DD + c0] = o;
      }
    }
  }
  __syncthreads();
  *(float4*)&red[tr][c0] = lsum;
  __syncthreads();
  if (tid < DD) {
    float s = 0.f;
#pragma unroll
    for (int t = 0; t < 16; ++t) s += red[t][tid];
    atomicAdd(&ssum[tid], s);
  }
  __syncthreads();
  *(float4*)&red[tr][c0] = lsq;
  __syncthreads();
  if (tid < DD) {
    float s = 0.f;
#pragma unroll
    for (int t = 0; t < 16; ++t) s += red[t][tid];
    atomicAdd(&ssq[tid], s);
  }
}

// ---------------- BN finalize: scale/shift ----------------
__global__ void bnfinal_kernel(const float* __restrict__ ssum, const float* __restrict__ ssq,
                               const float* __restrict__ gamma, const float* __restrict__ beta,
                               float invN, float* __restrict__ scale, float* __restrict__ shift) {
  int j = threadIdx.x;
  float m = ssum[j] * invN;
  float v = ssq[j] * invN - m * m;
  float sc = gamma[j] * rsqrtf(v + 1e-5f);
  scale[j] = sc;
  shift[j] = beta[j] - m * sc;
}

// ---------------- vectorized BN+ELU in place ----------------
__global__ void bn_elu_vec_kernel(float* __restrict__ x, long n4,
                                  const float* __restrict__ scale,
                                  const float* __restrict__ shift) {
  long stride = (long)gridDim.x * blockDim.x;
  for (long i = blockIdx.x * (long)blockDim.x + threadIdx.x; i < n4; i += stride) {
    float4 v = ((float4*)x)[i];
    int c0 = (int)((i & 15) << 2);
    float4 sc = *(const float4*)&scale[c0];
    float4 sh = *(const float4*)&shift[c0];
    v.x = elu_f(fmaf(v.x, sc.x, sh.x));
    v.y = elu_f(fmaf(v.y, sc.y, sh.y));
    v.z = elu_f(fmaf(v.z, sc.z, sh.z));
    v.w = elu_f(fmaf(v.w, sc.w, sh.w));
    ((float4*)x)[i] = v;
  }
}

// ---------------- pull aggregation: agg[a] = num/(den+eps), one wave per atom ----------------
__global__ __launch_bounds__(BLK) void agg_kernel(
    const float* __restrict__ e_act, const float* __restrict__ Eh,
    const int* __restrict__ start, const int* __restrict__ deg,
    const int2* __restrict__ adj, int na,
    float* __restrict__ aggout) {
  int wid = (int)((blockIdx.x * (unsigned)blockDim.x + threadIdx.x) >> 6);
  int lane = threadIdx.x & 63;
  if (wid >= na) return;
  int s = start[wid], d = deg[wid];
  float num = 0.f, den = 0.f;
  for (int k = 0; k < d; ++k) {
    int2 ent = adj[s + k];
    float ev = e_act[(size_t)ent.x * DD + lane];
    float sg = 1.f / (1.f + expf(-ev));
    float eh = Eh[(size_t)ent.y * DD + lane];
    num = fmaf(sg, eh, num);
    den += sg;
  }
  aggout[(size_t)wid * DD + lane] = num / (den + 1e-6f);
}

// ---------------- mol row-sum pull: out[m] = sum of src rows in list[start..start+cnt) ----------------
__global__ __launch_bounds__(BLK) void molsum_kernel(
    const float* __restrict__ src, const int* __restrict__ start,
    const int* __restrict__ cnt, const int* __restrict__ list, int nm,
    float* __restrict__ out) {
  int wid = (int)((blockIdx.x * (unsigned)blockDim.x + threadIdx.x) >> 6);
  int lane = threadIdx.x & 63;
  if (wid >= nm) return;
  int s = start[wid], c = cnt[wid];
  float acc = 0.f;
  for (int k = 0; k < c; ++k) {
    acc += src[(size_t)list[s + k] * DD + lane];
  }
  out[(size_t)wid * DD + lane] = acc;
}

// ---------------- atom pass 1: h_pre = (h@W3+b3 + agg + Fu[m])*norm ; BN stats ----------------
__global__ __launch_bounds__(BLK) void atom1_kernel(
    const float* __restrict__ h, int nrows, int ntiles,
    const float* __restrict__ W3, const float* __restrict__ b3,
    const float* __restrict__ Fu,
    const int* __restrict__ a2m, const float* __restrict__ nrm,
    float* __restrict__ hio,  // agg in, h_pre out (same buffer)
    float* __restrict__ ssum, float* __restrict__ ssq) {
  __shared__ __align__(16) float xs[TILE][DD + 4];
  __shared__ __align__(16) float wl[DD][DD];
  __shared__ int sam[TILE];
  __shared__ float sna[TILE];
  __shared__ __align__(16) float red[16][DD];
  const int tid = threadIdx.x;
  const int tr = tid >> 4, tc = tid & 15, r0 = tr * 4, c0 = tc * 4;
  for (int l = tid; l < DD * DD; l += BLK) wl[l >> 6][l & 63] = W3[l];
  float4 bp = *(const float4*)&b3[c0];
  float4 lsum = make_float4(0.f, 0.f, 0.f, 0.f);
  float4 lsq  = make_float4(0.f, 0.f, 0.f, 0.f);
  for (int tile = blockIdx.x; tile < ntiles; tile += gridDim.x) {
    const int base = tile * TILE;
    int rows = nrows - base; if (rows > TILE) rows = TILE;
    __syncthreads();
    for (int l = tid; l < TILE * DD; l += BLK) {
      int r = l >> 6, c = l & 63;
      xs[r][c] = (r < rows) ? h[(size_t)(base + r) * DD + c] : 0.f;
    }
    if (tid < TILE) {
      bool v = tid < rows;
      int rb = base + tid;
      sam[tid] = v ? a2m[rb] : 0;
      sna[tid] = v ? nrm[rb] : 0.f;
    }
    __syncthreads();
    float4 acc[4];
#pragma unroll
    for (int i = 0; i < 4; ++i) acc[i] = make_float4(0.f, 0.f, 0.f, 0.f);
    matmul_tile(xs, wl, r0, c0, acc);
#pragma unroll
    for (int i = 0; i < 4; ++i) {
      int r = r0 + i;
      if (r < rows) {
        size_t rb = (size_t)(base + r) * DD + c0;
        float na = sna[r];
        float4 g4 = *(const float4*)&hio[rb];
        float4 f4 = *(const float4*)&Fu[(size_t)sam[r] * DD + c0];
        float4 o;
        o.x = (acc[i].x + bp.x + g4.x + f4.x) * na;
        o.y = (acc[i].y + bp.y + g4.y + f4.y) * na;
        o.z = (acc[i].z + bp.z + g4.z + f4.z) * na;
        o.w = (acc[i].w + bp.w + g4.w + f4.w) * na;
        add4(lsum, o); sqacc4(lsq, o);
        *(float4*)&hio[rb] = o;
      }
    }
  }
  __syncthreads();
  *(float4*)&red[tr][c0] = lsum;
  __syncthreads();
  if (tid < DD) {
    float s = 0.f;
#pragma unroll
    for (int t = 0; t < 16; ++t) s += red[t][tid];
    atomicAdd(&ssum[tid], s);
  }
  __syncthreads();
  *(float4*)&red[tr][c0] = lsq;
  __syncthreads();
  if (tid < DD) {
    float s = 0.f;
#pragma unroll
    for (int t = 0; t < 16; ++t) s += red[t][tid];
    atomicAdd(&ssq[tid], s);
  }
}

// ---------------- global pass: u_pre = msa/cnt_a@W6 [+b6] + msb/cnt_b@W7 [+b7] + u@W8+b8 ----------------
__global__ __launch_bounds__(BLK) void global1_kernel(
    const float* __restrict__ u, int nrows,
    const float* __restrict__ W6, const float* __restrict__ W7, const float* __restrict__ W8,
    const float* __restrict__ b6, const float* __restrict__ b7, const float* __restrict__ b8,
    const float* __restrict__ msa, const float* __restrict__ msb,
    const int* __restrict__ cnta, const int* __restrict__ cntb,
    float* __restrict__ upre,
    float* __restrict__ ssum, float* __restrict__ ssq) {
  __shared__ __align__(16) float xsu[TILE][DD + 4];
  __shared__ __align__(16) float xsa[TILE][DD + 4];
  __shared__ __align__(16) float xsb[TILE][DD + 4];
  __shared__ __align__(16) float w6s[DD][DD];
  __shared__ __align__(16) float w7s[DD][DD];
  __shared__ __align__(16) float w8s[DD][DD];
  __shared__ float sfa[TILE], sfb[TILE];   // bias masks (cnt>0)
  __shared__ __align__(16) float red[16][DD];
  const int tid = threadIdx.x;
  const int base = blockIdx.x * TILE;
  int rows = nrows - base; if (rows > TILE) rows = TILE;
  for (int l = tid; l < DD * DD; l += BLK) {
    int r = l >> 6, c = l & 63;
    w6s[r][c] = W6[l];
    w7s[r][c] = W7[l];
    w8s[r][c] = W8[l];
  }
  for (int l = tid; l < TILE * DD; l += BLK) {
    int r = l >> 6, c = l & 63;
    bool v = r < rows;
    float ca = 1.f, cb = 1.f;
    if (v) {
      int ia = cnta[base + r], ib = cntb[base + r];
      ca = ia > 0 ? (float)ia : 1.f;
      cb = ib > 0 ? (float)ib : 1.f;
    }
    xsu[r][c] = v ? u[(size_t)(base + r) * DD + c] : 0.f;
    xsa[r][c] = v ? msa[(size_t)(base + r) * DD + c] / ca : 0.f;
    xsb[r][c] = v ? msb[(size_t)(base + r) * DD + c] / cb : 0.f;
  }
  if (tid < TILE) {
    bool v = tid < rows;
    sfa[tid] = (v && cnta[base + tid] > 0) ? 1.f : 0.f;
    sfb[tid] = (v && cntb[base + tid] > 0) ? 1.f : 0.f;
  }
  __syncthreads();
  const int tr = tid >> 4, tc = tid & 15, r0 = tr * 4, c0 = tc * 4;
  float4 acc[4];
#pragma unroll
  for (int i = 0; i < 4; ++i) acc[i] = make_float4(0.f, 0.f, 0.f, 0.f);
  matmul_tile(xsu, w8s, r0, c0, acc);
  matmul_tile(xsa, w6s, r0, c0, acc);
  matmul_tile(xsb, w7s, r0, c0, acc);
  float4 b6v = *(const float4*)&b6[c0];
  float4 b7v = *(const float4*)&b7[c0];
  float4 b8v = *(const float4*)&b8[c0];
  float4 lsum = make_float4(0.f, 0.f, 0.f, 0.f);
  float4 lsq  = make_float4(0.f, 0.f, 0.f, 0.f);
#pragma unroll
  for (int i = 0; i < 4; ++i) {
    int r = r0 + i;
    if (r < rows) {
      size_t rb = (size_t)(base + r) * DD + c0;
      float fa = sfa[r], fb = sfb[r];
      float4 o = acc[i];
      o.x += b8v.x + fa * b6v.x + fb * b7v.x;
      o.y += b8v.y + fa * b6v.y + fb * b7v.y;
      o.z += b8v.z + fa * b6v.z + fb * b7v.z;
      o.w += b8v.w + fa * b6v.w + fb * b7v.w;
      add4(lsum, o); sqacc4(lsq, o);
      *(float4*)&upre[rb] = o;
    }
  }
  __syncthreads();
  *(float4*)&red[tr][c0] = lsum;
  __syncthreads();
  if (tid < DD) {
    float s = 0.f;
#pragma unroll
    for (int t = 0; t < 16; ++t) s += red[t][tid];
    atomicAdd(&ssum[tid], s);
  }
  __syncthreads();
  *(float4*)&red[tr][c0] = lsq;
  __syncthreads();
  if (tid < DD) {
    float s = 0.f;
#pragma unroll
    for (int t = 0; t < 16; ++t) s += red[t][tid];
    atomicAdd(&ssq[tid], s);
  }
}

extern "C" void kernel_launch(void* const* d_in, const int* in_sizes, int n_in,
                              void* d_out, int out_size, void* d_ws, size_t ws_size,
                              hipStream_t stream) {
  const float* h         = (const float*)d_in[0];
  const float* e         = (const float*)d_in[1];
  const float* u         = (const float*)d_in[2];
  const float* norm_atom = (const float*)d_in[3];
  const float* norm_bond = (const float*)d_in[4];
  const float* Ws        = (const float*)d_in[5];
  const float* bsarr     = (const float*)d_in[6];
  const float* bn_gamma  = (const float*)d_in[7];
  const float* bn_beta   = (const float*)d_in[8];
  const int* bond_u      = (const int*)d_in[9];
  const int* bond_v      = (const int*)d_in[10];
  const int* a2m         = (const int*)d_in[11];
  const int* b2m         = (const int*)d_in[12];

  const int NA = in_sizes[0] / DD;
  const int NB = in_sizes[1] / DD;
  const int NM = in_sizes[2] / DD;

  float* out_h = (float*)d_out;
  float* out_e = out_h + (size_t)NA * DD;
  float* out_u = out_e + (size_t)NB * DD;

  // ---- workspace layout (~146 MB) ----
  float* f     = (float*)d_ws;
  float* Ah    = f;                            // NA*64
  float* Eh    = Ah + (size_t)NA * DD;         // NA*64
  float* Cu    = Eh + (size_t)NA * DD;         // NM*64
  float* Fu    = Cu + (size_t)NM * DD;         // NM*64
  float* msa   = Fu + (size_t)NM * DD;         // NM*64 (mol sum of h_new)
  float* msb   = msa + (size_t)NM * DD;        // NM*64 (mol sum of e_new)
  // zeroed block starts here:
  float* stats = msb + (size_t)NM * DD;        // 6*64
  float* sum_e = stats, *sq_e = stats + 64;
  float* sum_h = stats + 128, *sq_h = stats + 192;
  float* sum_u = stats + 256, *sq_u = stats + 320;
  int* deg     = (int*)(stats + 384);          // NA
  int* cur     = deg + NA;                     // NA
  int* cnta_i  = cur + NA;                     // NM
  int* cntb_i  = cnta_i + NM;                  // NM
  int* cur_ma  = cntb_i + NM;                  // NM
  int* cur_mb  = cur_ma + NM;                  // NM
  int* gcounts = cur_mb + NM;                  // 4
  // zeroed block ends here.
  float* bnp   = (float*)(gcounts + 4);        // 6*64
  float* sc_e = bnp, *sh_e = bnp + 64;
  float* sc_h = bnp + 128, *sh_h = bnp + 192;
  float* sc_u = bnp + 256, *sh_u = bnp + 320;
  int* start    = (int*)(bnp + 384);           // NA
  int* start_ma = start + NA;                  // NM
  int* start_mb = start_ma + NM;               // NM
  int* lista    = start_mb + NM;               // NA
  int* listb    = lista + NA;                  // NB
  int2* adj     = (int2*)(listb + NB);         // 2*NB (8B each)

  const float* W0 = Ws + 0 * 4096; const float* b0 = bsarr + 0 * 64;
  const float* W1 = Ws + 1 * 4096; const float* b1 = bsarr + 1 * 64;
  const float* W2 = Ws + 2 * 4096; const float* b2 = bsarr + 2 * 64;
  const float* W3 = Ws + 3 * 4096; const float* b3 = bsarr + 3 * 64;
  const float* W4 = Ws + 4 * 4096; const float* b4 = bsarr + 4 * 64;
  const float* W5 = Ws + 5 * 4096; const float* b5 = bsarr + 5 * 64;
  const float* W6 = Ws + 6 * 4096; const float* b6 = bsarr + 6 * 64;
  const float* W7 = Ws + 7 * 4096; const float* b7 = bsarr + 7 * 64;
  const float* W8 = Ws + 8 * 4096; const float* b8 = bsarr + 8 * 64;

  const int tiles_a = (NA + TILE - 1) / TILE;
  const int tiles_b = (NB + TILE - 1) / TILE;
  const int tiles_m = (NM + TILE - 1) / TILE;

  // zero: stats + deg + cur + mol counters + gcounts (contiguous)
  size_t zbytes = 384 * sizeof(float) + ((size_t)NA * 2 + (size_t)NM * 4 + 4) * sizeof(int);
  hipMemsetAsync(stats, 0, zbytes, stream);

  // counts + degrees
  cnt_kernel<<<(NA + NB + BLK - 1) / BLK, BLK, 0, stream>>>(a2m, NA, b2m, NB,
                                                            bond_u, bond_v,
                                                            cnta_i, cntb_i, deg);
  // CSR builds
  seg_alloc_kernel<<<(NA + BLK - 1) / BLK, BLK, 0, stream>>>(deg, NA, start, gcounts + 0);
  seg_alloc_kernel<<<(NM + BLK - 1) / BLK, BLK, 0, stream>>>(cnta_i, NM, start_ma, gcounts + 1);
  seg_alloc_kernel<<<(NM + BLK - 1) / BLK, BLK, 0, stream>>>(cntb_i, NM, start_mb, gcounts + 2);
  fill_kernel<<<(NB + BLK - 1) / BLK, BLK, 0, stream>>>(bond_u, bond_v, NB, start, cur, adj);
  fill_mol_kernel<<<(NA + NB + BLK - 1) / BLK, BLK, 0, stream>>>(a2m, NA, b2m, NB,
                                                                 start_ma, cur_ma, lista,
                                                                 start_mb, cur_mb, listb);

  lin2_kernel<<<tiles_a, BLK, 0, stream>>>(h, NA, W0, b0, Ah, W4, b4, Eh);
  lin2_kernel<<<tiles_m, BLK, 0, stream>>>(u, NM, W2, b2, Cu, W5, b5, Fu);

  int nblk_b = tiles_b < 2048 ? tiles_b : 2048;
  bond1_kernel<<<nblk_b, BLK, 0, stream>>>(e, NB, tiles_b, W1, b1, Ah, Cu,
                                           bond_u, bond_v, b2m, norm_bond,
                                           out_e, sum_e, sq_e);
  bnfinal_kernel<<<1, 64, 0, stream>>>(sum_e, sq_e, bn_gamma + 0, bn_beta + 0,
                                       1.f / (float)NB, sc_e, sh_e);

  // BN+ELU on e in place -> e_new
  {
    long n4 = (long)NB * (DD / 4);
    int blocks = (int)((n4 + BLK - 1) / BLK); if (blocks > 2048) blocks = 2048;
    bn_elu_vec_kernel<<<blocks, BLK, 0, stream>>>(out_e, n4, sc_e, sh_e);
  }

  // pull aggregation -> out_h holds num/(den+eps)
  agg_kernel<<<(NA + 3) / 4, BLK, 0, stream>>>(out_e, Eh, start, deg, adj, NA, out_h);

  int nblk_a = tiles_a < 2048 ? tiles_a : 2048;
  atom1_kernel<<<nblk_a, BLK, 0, stream>>>(h, NA, tiles_a, W3, b3, Fu,
                                           a2m, norm_atom, out_h, sum_h, sq_h);
  bnfinal_kernel<<<1, 64, 0, stream>>>(sum_h, sq_h, bn_gamma + 64, bn_beta + 64,
                                       1.f / (float)NA, sc_h, sh_h);

  // BN+ELU on h in place -> h_new
  {
    long n4 = (long)NA * (DD / 4);
    int blocks = (int)((n4 + BLK - 1) / BLK); if (blocks > 2048) blocks = 2048;
    bn_elu_vec_kernel<<<blocks, BLK, 0, stream>>>(out_h, n4, sc_h, sh_h);
  }

  // mol row-sums (pull, no atomics)
  molsum_kernel<<<(NM + 3) / 4, BLK, 0, stream>>>(out_h, start_ma, cnta_i, lista, NM, msa);
  molsum_kernel<<<(NM + 3) / 4, BLK, 0, stream>>>(out_e, start_mb, cntb_i, listb, NM, msb);

  global1_kernel<<<tiles_m, BLK, 0, stream>>>(u, NM, W6, W7, W8, b6, b7, b8,
                                              msa, msb, cnta_i, cntb_i,
                                              out_u, sum_u, sq_u);
  bnfinal_kernel<<<1, 64, 0, stream>>>(sum_u, sq_u, bn_gamma + 128, bn_beta + 128,
                                       1.f / (float)NM, sc_u, sh_u);
  {
    long n4 = (long)NM * (DD / 4);
    int blocks = (int)((n4 + BLK - 1) / BLK); if (blocks > 2048) blocks = 2048;
    bn_elu_vec_kernel<<<blocks, BLK, 0, stream>>>(out_u, n4, sc_u, sh_u);
  }
}